// Round 1
// 952.069 us; speedup vs baseline: 1.0363x; 1.0363x over previous
//
#include <hip/hip_runtime.h>
#include <cstdint>
#include <cstddef>

#define BB 256
#define TT 250
#define DIN 700
#define H1 256
#define H2 256
#define DOUT 20
#define BJ0 0.01f
#define BETAC 1.8f
#define DUMMY 256                 // zero row index in every padded table
#define IQSCALE 3.814697265625e-06f   // 2^-18

typedef float f32x4 __attribute__((ext_vector_type(4)));
typedef short s16x4 __attribute__((ext_vector_type(4)));

// ---------------------------------------------------------------------------
// Workspace layout:
//   sT1  [701*256] shorts @ s0        (row 700 = zeros)           bytes [0,358912)
//   sP12 [257*256] ints   @ i89728    lo=w_h12h1, hi=w_h12h2 q18  bytes [358912,622080)
//   sT22 [257*256] shorts @ s311040   (row 256 = zeros)           bytes [622080,753664)
//   wT2o [257*20]  floats @ f188416   (row 256 = zeros)
//   Xp   [256*250*256] floats @ f193556
// ---------------------------------------------------------------------------
#define IOFF_P12 89728
#define SOFF_T22 311040
#define FOFF_W2O 188416
#define FOFF_XP  193556
#define N_TRANS  316180

__device__ __forceinline__ short q18(float w) {
    float s = w * 262144.0f;
    s = fminf(fmaxf(s, -32767.0f), 32767.0f);
    return (short)__float2int_rn(s);
}

__global__ void transpose_all_k(const float* __restrict__ w_i2h1,
                                const float* __restrict__ w_h12h1,
                                const float* __restrict__ w_h12h2,
                                const float* __restrict__ w_h22h2,
                                const float* __restrict__ w_h2o,
                                short* __restrict__ sws,
                                float* __restrict__ fws) {
    int i = blockIdx.x * blockDim.x + threadIdx.x;
    if (i < 179456) { int d = i >> 8, h = i & 255;
        sws[i] = q18((d < DIN) ? w_i2h1[h * DIN + d] : 0.f); return; }
    i -= 179456;
    if (i < 65792) { int d = i >> 8, h = i & 255;
        unsigned int lo = 0, hi = 0;
        if (d < H1) {
            lo = (unsigned short)q18(w_h12h1[h * H1 + d]);
            hi = (unsigned short)q18(w_h12h2[h * H1 + d]);
        }
        ((int*)sws)[IOFF_P12 + i] = (int)(lo | (hi << 16)); return; }
    i -= 65792;
    if (i < 65792) { int d = i >> 8, h = i & 255;
        sws[SOFF_T22 + i] = q18((d < H2) ? w_h22h2[h * H2 + d] : 0.f); return; }
    i -= 65792;
    if (i < 5140)  { int j = i / 20, h = i % 20;
        fws[FOFF_W2O + i] = (j < H2) ? w_h2o[h * H2 + j] : 0.f; return; }
}

// ---------------------------------------------------------------------------
// Xp[b][t][h] = b_h1[h] + (Σ_{d active} sT1[d*256+h]) * 2^-18
// (16-row unrolled gather: deeper memory-level parallelism per lgkm wait)
// ---------------------------------------------------------------------------
__global__ __launch_bounds__(256) void xproj_k(const float* __restrict__ x,
                                               const short* __restrict__ sT1,
                                               const float* __restrict__ b_h1,
                                               float* __restrict__ Xp) {
    const int lane = threadIdx.x & 63;
    const int wv   = threadIdx.x >> 6;
    const int bt   = blockIdx.x * 4 + wv;   // grid = B*T/4 = 16000
    const int b    = bt / TT;
    const int t    = bt - b * TT;

    __shared__ __align__(16) int lst[4][712];

    const float* xrow = x + ((size_t)b * TT + t) * DIN;
    float xv[11];
    #pragma unroll
    for (int c = 0; c < 11; ++c) {
        int d = c * 64 + lane;
        xv[c] = (d < DIN) ? __builtin_nontemporal_load(xrow + d) : 0.f;
    }
    int cnt = 0;
    #pragma unroll
    for (int c = 0; c < 11; ++c) {
        int d = c * 64 + lane;
        bool p = (xv[c] != 0.0f);
        unsigned long long m = __ballot(p ? 1 : 0);
        if (p) {
            int pos = cnt + __popcll(m & ((1ull << lane) - 1ull));
            lst[wv][pos] = d;
        }
        cnt += __popcll(m);
    }
    int cntp = (cnt + 15) & ~15;
    if (lane < cntp - cnt) lst[wv][cnt + lane] = DIN;   // zero row pad
    __syncthreads();

    const int lo = lane * 4;
    int i0 = 0, i1 = 0, i2 = 0, i3 = 0;
    int j0 = 0, j1 = 0, j2 = 0, j3 = 0;
    for (int k = 0; k < cntp; k += 16) {
        int4 ja = *(const int4*)&lst[wv][k];
        int4 jb = *(const int4*)&lst[wv][k + 4];
        int4 jc = *(const int4*)&lst[wv][k + 8];
        int4 jd = *(const int4*)&lst[wv][k + 12];
        s16x4 w0  = *(const s16x4*)(sT1 + ((size_t)ja.x << 8) + lo);
        s16x4 w1  = *(const s16x4*)(sT1 + ((size_t)ja.y << 8) + lo);
        s16x4 w2  = *(const s16x4*)(sT1 + ((size_t)ja.z << 8) + lo);
        s16x4 w3  = *(const s16x4*)(sT1 + ((size_t)ja.w << 8) + lo);
        s16x4 w4  = *(const s16x4*)(sT1 + ((size_t)jb.x << 8) + lo);
        s16x4 w5  = *(const s16x4*)(sT1 + ((size_t)jb.y << 8) + lo);
        s16x4 w6  = *(const s16x4*)(sT1 + ((size_t)jb.z << 8) + lo);
        s16x4 w7  = *(const s16x4*)(sT1 + ((size_t)jb.w << 8) + lo);
        s16x4 w8  = *(const s16x4*)(sT1 + ((size_t)jc.x << 8) + lo);
        s16x4 w9  = *(const s16x4*)(sT1 + ((size_t)jc.y << 8) + lo);
        s16x4 w10 = *(const s16x4*)(sT1 + ((size_t)jc.z << 8) + lo);
        s16x4 w11 = *(const s16x4*)(sT1 + ((size_t)jc.w << 8) + lo);
        s16x4 w12 = *(const s16x4*)(sT1 + ((size_t)jd.x << 8) + lo);
        s16x4 w13 = *(const s16x4*)(sT1 + ((size_t)jd.y << 8) + lo);
        s16x4 w14 = *(const s16x4*)(sT1 + ((size_t)jd.z << 8) + lo);
        s16x4 w15 = *(const s16x4*)(sT1 + ((size_t)jd.w << 8) + lo);
        i0 += ((w0.x + w1.x) + (w2.x + w3.x)) + ((w4.x + w5.x) + (w6.x + w7.x));
        i1 += ((w0.y + w1.y) + (w2.y + w3.y)) + ((w4.y + w5.y) + (w6.y + w7.y));
        i2 += ((w0.z + w1.z) + (w2.z + w3.z)) + ((w4.z + w5.z) + (w6.z + w7.z));
        i3 += ((w0.w + w1.w) + (w2.w + w3.w)) + ((w4.w + w5.w) + (w6.w + w7.w));
        j0 += ((w8.x + w9.x) + (w10.x + w11.x)) + ((w12.x + w13.x) + (w14.x + w15.x));
        j1 += ((w8.y + w9.y) + (w10.y + w11.y)) + ((w12.y + w13.y) + (w14.y + w15.y));
        j2 += ((w8.z + w9.z) + (w10.z + w11.z)) + ((w12.z + w13.z) + (w14.z + w15.z));
        j3 += ((w8.w + w9.w) + (w10.w + w11.w)) + ((w12.w + w13.w) + (w14.w + w15.w));
    }
    f32x4 acc = *(const f32x4*)(b_h1 + lo);
    acc.x += (float)(i0 + j0) * IQSCALE;
    acc.y += (float)(i1 + j1) * IQSCALE;
    acc.z += (float)(i2 + j2) * IQSCALE;
    acc.w += (float)(i3 + j3) * IQSCALE;
    __builtin_nontemporal_store(acc, (f32x4*)(Xp + ((size_t)b * TT + t) * H1 + lo));
}

// ---------------------------------------------------------------------------
// rec_k: 512 threads = 8 gather groups of 64 lanes.
//   Gather phase (all 8 waves): group g walks list entries k≡g (mod 8) from
//   SEGMENTED lists (contiguous per group → int4 entry loads, no dependent
//   LDS chain). Lane l owns cols 4l..4l+3:
//     - sP12 row: one global dwordx4 gives W11 (lo16) + W12 (hi16) for 4 cols
//     - sT22L row: one ds_read_b64 (s16x4)
//     - wT2o row: one float4 (lanes 0..4 only, cols 0..19)
//   Partials → LDS pp11/pp12/pp22/pro; barrier; primary 256 threads combine
//   and run U1(i), U2(i-1), output/softmax(i-2) exactly as before.
// Integer sums are re-associations of the previous kernel's sums → the
// spike-deciding path is bit-identical.
// LDS: 131584 + 2*1024 + 3*8192 + 640 + 64 + 80 = 158,992 B (1 block/CU).
// ---------------------------------------------------------------------------
__global__ __launch_bounds__(512) void rec_k(
    const float* __restrict__ Xp,
    const int*   __restrict__ sP12,
    const short* __restrict__ sT22, const float* __restrict__ wT2o,
    const float* __restrict__ b_h2, const float* __restrict__ b_o,
    const float* __restrict__ tau_adp_h1, const float* __restrict__ tau_adp_h2,
    const float* __restrict__ tau_m_h1, const float* __restrict__ tau_m_h2,
    const float* __restrict__ tau_m_o,
    float* __restrict__ out) {
    const int tid  = threadIdx.x;        // 0..511
    const int h    = tid & 255;
    const int half = tid >> 8;           // 0 = primary (U/rebuild), 1 = secondary
    const int lane = tid & 63;
    const int g    = tid >> 6;           // gather group 0..7
    const int wvp  = g & 3;              // wave index within half
    const int l4   = lane << 2;          // 4-column base
    const int b    = blockIdx.x;
    const float* __restrict__ XpB = Xp + (size_t)b * TT * H1;

    __shared__ __align__(16) short sT22L[65792];   // 257*256 int16 = 128.5 KB
    __shared__ __align__(16) int lst1s[256];       // 8 segments x 32 slots
    __shared__ __align__(16) int lst2s[256];
    __shared__ __align__(16) int pp11[8][256];
    __shared__ __align__(16) int pp12[8][256];
    __shared__ __align__(16) int pp22[8][256];
    __shared__ __align__(16) float pro[8][20];
    __shared__ unsigned long long wm1[4];
    __shared__ unsigned long long wm2[4];
    __shared__ float smo[DOUT];

    // one-time staging: sT22 (dword copy)
    {
        const int* src = (const int*)sT22;
        int* dst = (int*)sT22L;
        for (int i2 = tid; i2 < 32896; i2 += 512) dst[i2] = src[i2];
    }

    const float alpha1 = expf(-1.0f / tau_m_h1[h]);
    const float ro1    = expf(-1.0f / tau_adp_h1[h]);
    const float alpha2 = expf(-1.0f / tau_m_h2[h]);
    const float ro2    = expf(-1.0f / tau_adp_h2[h]);
    const float bh2v   = b_h2[h];
    float alpo = 0.f, bov = 0.f;
    if (h < DOUT) { alpo = expf(-1.0f / tau_m_o[h]); bov = b_o[h]; }

    float mem1 = 0.f, spk1 = 0.f, bb1v = BJ0;
    float mem2 = 0.f, spk2 = 0.f, bb2v = BJ0;
    float memo = 0.f, accs = 0.f;
    int n1p = 0, n2p = 0;

    float xp_cur = 0.f;
    if (half == 0) xp_cur = __builtin_nontemporal_load(XpB + h);
    __syncthreads();                       // staging complete

    for (int i = 0; i <= TT + 1; ++i) {
        float xp_nxt = 0.f;
        if (half == 0 && i + 1 < TT)
            xp_nxt = __builtin_nontemporal_load(XpB + (size_t)(i + 1) * H1 + h);

        const bool dmo = (h < DOUT) && (i >= 2);

        // ---- gather phase (all 512 threads) ----
        int a110 = 0, a111 = 0, a112 = 0, a113 = 0;
        int a120 = 0, a121 = 0, a122 = 0, a123 = 0;
        int a220 = 0, a221 = 0, a222 = 0, a223 = 0;
        float ao0 = 0.f, ao1 = 0.f, ao2 = 0.f, ao3 = 0.f;

        const int ng1 = n1p >> 3;                       // multiple of 4
        for (int kk = 0; kk < ng1; kk += 4) {
            int4 e = *(const int4*)&lst1s[(g << 5) + kk];
            int4 pa = *(const int4*)(sP12 + ((size_t)e.x << 8) + l4);
            int4 pb = *(const int4*)(sP12 + ((size_t)e.y << 8) + l4);
            int4 pc = *(const int4*)(sP12 + ((size_t)e.z << 8) + l4);
            int4 pd = *(const int4*)(sP12 + ((size_t)e.w << 8) + l4);
            a110 += ((int)(short)pa.x + (int)(short)pb.x) + ((int)(short)pc.x + (int)(short)pd.x);
            a111 += ((int)(short)pa.y + (int)(short)pb.y) + ((int)(short)pc.y + (int)(short)pd.y);
            a112 += ((int)(short)pa.z + (int)(short)pb.z) + ((int)(short)pc.z + (int)(short)pd.z);
            a113 += ((int)(short)pa.w + (int)(short)pb.w) + ((int)(short)pc.w + (int)(short)pd.w);
            a120 += ((pa.x >> 16) + (pb.x >> 16)) + ((pc.x >> 16) + (pd.x >> 16));
            a121 += ((pa.y >> 16) + (pb.y >> 16)) + ((pc.y >> 16) + (pd.y >> 16));
            a122 += ((pa.z >> 16) + (pb.z >> 16)) + ((pc.z >> 16) + (pd.z >> 16));
            a123 += ((pa.w >> 16) + (pb.w >> 16)) + ((pc.w >> 16) + (pd.w >> 16));
        }
        const int ng2 = n2p >> 3;                       // multiple of 4
        for (int kk = 0; kk < ng2; kk += 4) {
            int4 e = *(const int4*)&lst2s[(g << 5) + kk];
            s16x4 wa = *(const s16x4*)(sT22L + (e.x << 8) + l4);
            s16x4 wb = *(const s16x4*)(sT22L + (e.y << 8) + l4);
            s16x4 wc = *(const s16x4*)(sT22L + (e.z << 8) + l4);
            s16x4 wd = *(const s16x4*)(sT22L + (e.w << 8) + l4);
            a220 += (wa.x + wb.x) + (wc.x + wd.x);
            a221 += (wa.y + wb.y) + (wc.y + wd.y);
            a222 += (wa.z + wb.z) + (wc.z + wd.z);
            a223 += (wa.w + wb.w) + (wc.w + wd.w);
            if (lane < 5) {
                float4 va = *(const float4*)(wT2o + e.x * DOUT + l4);
                float4 vb = *(const float4*)(wT2o + e.y * DOUT + l4);
                float4 vc = *(const float4*)(wT2o + e.z * DOUT + l4);
                float4 vd = *(const float4*)(wT2o + e.w * DOUT + l4);
                ao0 += (va.x + vb.x) + (vc.x + vd.x);
                ao1 += (va.y + vb.y) + (vc.y + vd.y);
                ao2 += (va.z + vb.z) + (vc.z + vd.z);
                ao3 += (va.w + vb.w) + (vc.w + vd.w);
            }
        }
        {
            int4 v;
            v.x = a110; v.y = a111; v.z = a112; v.w = a113;
            *(int4*)&pp11[g][l4] = v;
            v.x = a120; v.y = a121; v.z = a122; v.w = a123;
            *(int4*)&pp12[g][l4] = v;
            v.x = a220; v.y = a221; v.z = a222; v.w = a223;
            *(int4*)&pp22[g][l4] = v;
        }
        if (lane < 5) {
            float4 v; v.x = ao0; v.y = ao1; v.z = ao2; v.w = ao3;
            *(float4*)&pro[g][l4] = v;
        }
        __syncthreads();                               // B0: partials visible

        // ---- update phase (primary half only) ----
        unsigned long long m1 = 0, m2 = 0;
        float ns1 = 0.f, ns2 = 0.f;
        if (half == 0) {
            int ir11 = ((pp11[0][h] + pp11[1][h]) + (pp11[2][h] + pp11[3][h]))
                     + ((pp11[4][h] + pp11[5][h]) + (pp11[6][h] + pp11[7][h]));
            int ir12 = ((pp12[0][h] + pp12[1][h]) + (pp12[2][h] + pp12[3][h]))
                     + ((pp12[4][h] + pp12[5][h]) + (pp12[6][h] + pp12[7][h]));
            int ir22 = ((pp22[0][h] + pp22[1][h]) + (pp22[2][h] + pp22[3][h]))
                     + ((pp22[4][h] + pp22[5][h]) + (pp22[6][h] + pp22[7][h]));
            if (i < TT) {
                float r1 = (float)ir11 * IQSCALE;
                bb1v = ro1 * bb1v + BETAC * (1.f - ro1) * spk1;
                mem1 = mem1 * alpha1 - bb1v * spk1 + (1.f - alpha1) * (xp_cur + r1);
                ns1 = (mem1 - bb1v - BJ0) > 0.f ? 1.f : 0.f;
                spk1 = ns1;
                m1 = __ballot(ns1 != 0.f ? 1 : 0);
                if (lane == 0) wm1[wvp] = m1;
            }
            if (i >= 1 && i <= TT) {
                float r23 = (float)(ir22 + ir12) * IQSCALE;
                bb2v = ro2 * bb2v + BETAC * (1.f - ro2) * spk2;
                mem2 = mem2 * alpha2 - bb2v * spk2 + (1.f - alpha2) * (bh2v + r23);
                ns2 = (mem2 - bb2v - BJ0) > 0.f ? 1.f : 0.f;
                spk2 = ns2;
                m2 = __ballot(ns2 != 0.f ? 1 : 0);
                if (lane == 0) wm2[wvp] = m2;
            }
            if (dmo) {
                float ro = ((pro[0][h] + pro[1][h]) + (pro[2][h] + pro[3][h]))
                         + ((pro[4][h] + pro[5][h]) + (pro[6][h] + pro[7][h]));
                memo = memo * alpo + (1.f - alpo) * (bov + ro);
                smo[h] = memo;
            }
        }
        __syncthreads();                               // B1

        // ---- rebuild lst1 <- spk1(i), segmented: pos p -> seg p&7 slot p>>3
        if (i < TT) {
            unsigned long long q0 = wm1[0], q1 = wm1[1], q2 = wm1[2], q3 = wm1[3];
            int tot = (__popcll(q0) + __popcll(q1)) + (__popcll(q2) + __popcll(q3));
            if (half == 0) {
                int pos = __popcll(m1 & ((1ull << lane) - 1ull));
                if (wvp > 0) pos += __popcll(q0);
                if (wvp > 1) pos += __popcll(q1);
                if (wvp > 2) pos += __popcll(q2);
                if (ns1 != 0.f) lst1s[((pos & 7) << 5) + (pos >> 3)] = h;
                int np = (tot + 31) & ~31;
                if (h < np - tot) {
                    int p2 = tot + h;
                    lst1s[((p2 & 7) << 5) + (p2 >> 3)] = DUMMY;
                }
            }
            n1p = (tot + 31) & ~31;
        } else {
            n1p = 0;
        }
        // ---- rebuild lst2 <- spk2(i-1) ----
        if (i >= 1 && i <= TT) {
            unsigned long long q0 = wm2[0], q1 = wm2[1], q2 = wm2[2], q3 = wm2[3];
            int tot = (__popcll(q0) + __popcll(q1)) + (__popcll(q2) + __popcll(q3));
            if (half == 0) {
                int pos = __popcll(m2 & ((1ull << lane) - 1ull));
                if (wvp > 0) pos += __popcll(q0);
                if (wvp > 1) pos += __popcll(q1);
                if (wvp > 2) pos += __popcll(q2);
                if (ns2 != 0.f) lst2s[((pos & 7) << 5) + (pos >> 3)] = h;
                int np = (tot + 31) & ~31;
                if (h < np - tot) {
                    int p2 = tot + h;
                    lst2s[((p2 & 7) << 5) + (p2 >> 3)] = DUMMY;
                }
            }
            n2p = (tot + 31) & ~31;
        }
        // ---- softmax accum for step i-2 ----
        if (half == 0 && dmo) {
            float mx = smo[0];
            #pragma unroll
            for (int j = 1; j < DOUT; ++j) mx = fmaxf(mx, smo[j]);
            float s = 0.f;
            #pragma unroll
            for (int j = 0; j < DOUT; ++j) s += __expf(smo[j] - mx);
            accs += __expf(memo - mx) / s;
        }
        __syncthreads();                               // B2

        xp_cur = xp_nxt;
    }

    if (half == 0 && h < DOUT) out[b * DOUT + h] = accs;
}

extern "C" void kernel_launch(void* const* d_in, const int* in_sizes, int n_in,
                              void* d_out, int out_size, void* d_ws, size_t ws_size,
                              hipStream_t stream) {
    const float* x          = (const float*)d_in[0];
    const float* w_i2h1     = (const float*)d_in[1];
    const float* w_h12h1    = (const float*)d_in[2];
    const float* w_h12h2    = (const float*)d_in[3];
    const float* w_h22h2    = (const float*)d_in[4];
    const float* w_h2o      = (const float*)d_in[5];
    const float* b_h1       = (const float*)d_in[6];
    const float* b_h2       = (const float*)d_in[7];
    const float* b_o        = (const float*)d_in[8];
    const float* tau_adp_h1 = (const float*)d_in[9];
    const float* tau_adp_h2 = (const float*)d_in[10];
    const float* tau_m_h1   = (const float*)d_in[11];
    const float* tau_m_h2   = (const float*)d_in[12];
    const float* tau_m_o    = (const float*)d_in[13];

    short* sws = (short*)d_ws;
    float* fws = (float*)d_ws;
    const short* sT1  = sws;
    const int*   sP12 = (const int*)d_ws + IOFF_P12;
    const short* sT22 = sws + SOFF_T22;
    float* wT2o = fws + FOFF_W2O;
    float* Xp   = fws + FOFF_XP;

    transpose_all_k<<<(N_TRANS + 255) / 256, 256, 0, stream>>>(
        w_i2h1, w_h12h1, w_h12h2, w_h22h2, w_h2o, sws, fws);

    xproj_k<<<(BB * TT) / 4, 256, 0, stream>>>(x, sT1, b_h1, Xp);

    rec_k<<<BB, 512, 0, stream>>>(Xp, sP12, sT22, wT2o,
                                  b_h2, b_o, tau_adp_h1, tau_adp_h2,
                                  tau_m_h1, tau_m_h2, tau_m_o,
                                  (float*)d_out);
}

// Round 2
// 896.983 us; speedup vs baseline: 1.0999x; 1.0614x over previous
//
#include <hip/hip_runtime.h>
#include <cstdint>
#include <cstddef>

#define BB 256
#define TT 250
#define DIN 700
#define H1 256
#define H2 256
#define DOUT 20
#define BJ0 0.01f
#define BETAC 1.8f
#define DUMMY 256                 // zero row index in every padded table
#define IQSCALE 3.814697265625e-06f   // 2^-18

typedef float f32x4 __attribute__((ext_vector_type(4)));
typedef short s16x4 __attribute__((ext_vector_type(4)));

// ---------------------------------------------------------------------------
// Workspace layout:
//   sT1  [701*256] shorts @ s0        (row 700 = zeros)           bytes [0,358912)
//   sP12 [257*256] ints   @ i89728    lo=w_h12h1, hi=w_h12h2 q18  bytes [358912,622080)
//   sT22 [257*256] shorts @ s311040   (row 256 = zeros)           bytes [622080,753664)
//   wT2o [257*20]  floats @ f188416   (row 256 = zeros)
//   Xp   [256*250*256] floats @ f193556
//   Mo   [256*250*20]  floats @ f16577556   (per-step output membrane)
// ---------------------------------------------------------------------------
#define IOFF_P12 89728
#define SOFF_T22 311040
#define FOFF_W2O 188416
#define FOFF_XP  193556
#define FOFF_MO  16577556
#define N_TRANS  316180

// LDS-only drain + raw barrier: cross-thread data in rec_k flows exclusively
// through LDS, so we need not drain vmcnt (global loads stay in flight across
// the barrier — this is what lets the Xp prefetch actually span an iteration).
#define BARRIER_LDS() asm volatile("s_waitcnt lgkmcnt(0)\n\ts_barrier" ::: "memory")

__device__ __forceinline__ short q18(float w) {
    float s = w * 262144.0f;
    s = fminf(fmaxf(s, -32767.0f), 32767.0f);
    return (short)__float2int_rn(s);
}

__global__ void transpose_all_k(const float* __restrict__ w_i2h1,
                                const float* __restrict__ w_h12h1,
                                const float* __restrict__ w_h12h2,
                                const float* __restrict__ w_h22h2,
                                const float* __restrict__ w_h2o,
                                short* __restrict__ sws,
                                float* __restrict__ fws) {
    int i = blockIdx.x * blockDim.x + threadIdx.x;
    if (i < 179456) { int d = i >> 8, h = i & 255;
        sws[i] = q18((d < DIN) ? w_i2h1[h * DIN + d] : 0.f); return; }
    i -= 179456;
    if (i < 65792) { int d = i >> 8, h = i & 255;
        unsigned int lo = 0, hi = 0;
        if (d < H1) {
            lo = (unsigned short)q18(w_h12h1[h * H1 + d]);
            hi = (unsigned short)q18(w_h12h2[h * H1 + d]);
        }
        ((int*)sws)[IOFF_P12 + i] = (int)(lo | (hi << 16)); return; }
    i -= 65792;
    if (i < 65792) { int d = i >> 8, h = i & 255;
        sws[SOFF_T22 + i] = q18((d < H2) ? w_h22h2[h * H2 + d] : 0.f); return; }
    i -= 65792;
    if (i < 5140)  { int j = i / 20, h = i % 20;
        fws[FOFF_W2O + i] = (j < H2) ? w_h2o[h * H2 + j] : 0.f; return; }
}

// ---------------------------------------------------------------------------
// Xp[b][t][h] = b_h1[h] + (Σ_{d active} sT1[d*256+h]) * 2^-18
// ---------------------------------------------------------------------------
__global__ __launch_bounds__(256) void xproj_k(const float* __restrict__ x,
                                               const short* __restrict__ sT1,
                                               const float* __restrict__ b_h1,
                                               float* __restrict__ Xp) {
    const int lane = threadIdx.x & 63;
    const int wv   = threadIdx.x >> 6;
    const int bt   = blockIdx.x * 4 + wv;   // grid = B*T/4 = 16000
    const int b    = bt / TT;
    const int t    = bt - b * TT;

    __shared__ __align__(16) int lst[4][712];

    const float* xrow = x + ((size_t)b * TT + t) * DIN;
    float xv[11];
    #pragma unroll
    for (int c = 0; c < 11; ++c) {
        int d = c * 64 + lane;
        xv[c] = (d < DIN) ? __builtin_nontemporal_load(xrow + d) : 0.f;
    }
    int cnt = 0;
    #pragma unroll
    for (int c = 0; c < 11; ++c) {
        int d = c * 64 + lane;
        bool p = (xv[c] != 0.0f);
        unsigned long long m = __ballot(p ? 1 : 0);
        if (p) {
            int pos = cnt + __popcll(m & ((1ull << lane) - 1ull));
            lst[wv][pos] = d;
        }
        cnt += __popcll(m);
    }
    int cntp = (cnt + 15) & ~15;
    if (lane < cntp - cnt) lst[wv][cnt + lane] = DIN;   // zero row pad
    __syncthreads();

    const int lo = lane * 4;
    int i0 = 0, i1 = 0, i2 = 0, i3 = 0;
    int j0 = 0, j1 = 0, j2 = 0, j3 = 0;
    for (int k = 0; k < cntp; k += 16) {
        int4 ja = *(const int4*)&lst[wv][k];
        int4 jb = *(const int4*)&lst[wv][k + 4];
        int4 jc = *(const int4*)&lst[wv][k + 8];
        int4 jd = *(const int4*)&lst[wv][k + 12];
        s16x4 w0  = *(const s16x4*)(sT1 + ((size_t)ja.x << 8) + lo);
        s16x4 w1  = *(const s16x4*)(sT1 + ((size_t)ja.y << 8) + lo);
        s16x4 w2  = *(const s16x4*)(sT1 + ((size_t)ja.z << 8) + lo);
        s16x4 w3  = *(const s16x4*)(sT1 + ((size_t)ja.w << 8) + lo);
        s16x4 w4  = *(const s16x4*)(sT1 + ((size_t)jb.x << 8) + lo);
        s16x4 w5  = *(const s16x4*)(sT1 + ((size_t)jb.y << 8) + lo);
        s16x4 w6  = *(const s16x4*)(sT1 + ((size_t)jb.z << 8) + lo);
        s16x4 w7  = *(const s16x4*)(sT1 + ((size_t)jb.w << 8) + lo);
        s16x4 w8  = *(const s16x4*)(sT1 + ((size_t)jc.x << 8) + lo);
        s16x4 w9  = *(const s16x4*)(sT1 + ((size_t)jc.y << 8) + lo);
        s16x4 w10 = *(const s16x4*)(sT1 + ((size_t)jc.z << 8) + lo);
        s16x4 w11 = *(const s16x4*)(sT1 + ((size_t)jc.w << 8) + lo);
        s16x4 w12 = *(const s16x4*)(sT1 + ((size_t)jd.x << 8) + lo);
        s16x4 w13 = *(const s16x4*)(sT1 + ((size_t)jd.y << 8) + lo);
        s16x4 w14 = *(const s16x4*)(sT1 + ((size_t)jd.z << 8) + lo);
        s16x4 w15 = *(const s16x4*)(sT1 + ((size_t)jd.w << 8) + lo);
        i0 += ((w0.x + w1.x) + (w2.x + w3.x)) + ((w4.x + w5.x) + (w6.x + w7.x));
        i1 += ((w0.y + w1.y) + (w2.y + w3.y)) + ((w4.y + w5.y) + (w6.y + w7.y));
        i2 += ((w0.z + w1.z) + (w2.z + w3.z)) + ((w4.z + w5.z) + (w6.z + w7.z));
        i3 += ((w0.w + w1.w) + (w2.w + w3.w)) + ((w4.w + w5.w) + (w6.w + w7.w));
        j0 += ((w8.x + w9.x) + (w10.x + w11.x)) + ((w12.x + w13.x) + (w14.x + w15.x));
        j1 += ((w8.y + w9.y) + (w10.y + w11.y)) + ((w12.y + w13.y) + (w14.y + w15.y));
        j2 += ((w8.z + w9.z) + (w10.z + w11.z)) + ((w12.z + w13.z) + (w14.z + w15.z));
        j3 += ((w8.w + w9.w) + (w10.w + w11.w)) + ((w12.w + w13.w) + (w14.w + w15.w));
    }
    f32x4 acc = *(const f32x4*)(b_h1 + lo);
    acc.x += (float)(i0 + j0) * IQSCALE;
    acc.y += (float)(i1 + j1) * IQSCALE;
    acc.z += (float)(i2 + j2) * IQSCALE;
    acc.w += (float)(i3 + j3) * IQSCALE;
    __builtin_nontemporal_store(acc, (f32x4*)(Xp + ((size_t)b * TT + t) * H1 + lo));
}

// ---------------------------------------------------------------------------
// rec_k: 512 threads = 8 gather groups of 64 lanes (R1 structure), with:
//   - raw barriers (lgkmcnt-only drain): global loads stay in flight across
//     barriers, so the Xp prefetch really does span a full iteration.
//   - softmax removed from the loop: memo(t) for h<20 goes to global Mo,
//     a separate fully-parallel soft_k does softmax+accumulate.
// Integer spike-deciding path bit-identical to R1.
// ---------------------------------------------------------------------------
__global__ __launch_bounds__(512) void rec_k(
    const float* __restrict__ Xp,
    const int*   __restrict__ sP12,
    const short* __restrict__ sT22, const float* __restrict__ wT2o,
    const float* __restrict__ b_h2, const float* __restrict__ b_o,
    const float* __restrict__ tau_adp_h1, const float* __restrict__ tau_adp_h2,
    const float* __restrict__ tau_m_h1, const float* __restrict__ tau_m_h2,
    const float* __restrict__ tau_m_o,
    float* __restrict__ Mo) {
    const int tid  = threadIdx.x;        // 0..511
    const int h    = tid & 255;
    const int half = tid >> 8;           // 0 = primary (U/rebuild), 1 = secondary
    const int lane = tid & 63;
    const int g    = tid >> 6;           // gather group 0..7
    const int wvp  = g & 3;              // wave index within half
    const int l4   = lane << 2;          // 4-column base
    const int b    = blockIdx.x;
    const float* __restrict__ XpB = Xp + (size_t)b * TT * H1;
    float* __restrict__ MoB = Mo + (size_t)b * TT * DOUT;

    __shared__ __align__(16) short sT22L[65792];   // 257*256 int16 = 128.5 KB
    __shared__ __align__(16) int lst1s[256];       // 8 segments x 32 slots
    __shared__ __align__(16) int lst2s[256];
    __shared__ __align__(16) int pp11[8][256];
    __shared__ __align__(16) int pp12[8][256];
    __shared__ __align__(16) int pp22[8][256];
    __shared__ __align__(16) float pro[8][20];
    __shared__ unsigned long long wm1[4];
    __shared__ unsigned long long wm2[4];

    // one-time staging: sT22 (dword copy)
    {
        const int* src = (const int*)sT22;
        int* dst = (int*)sT22L;
        for (int i2 = tid; i2 < 32896; i2 += 512) dst[i2] = src[i2];
    }

    const float alpha1 = expf(-1.0f / tau_m_h1[h]);
    const float ro1    = expf(-1.0f / tau_adp_h1[h]);
    const float alpha2 = expf(-1.0f / tau_m_h2[h]);
    const float ro2    = expf(-1.0f / tau_adp_h2[h]);
    const float bh2v   = b_h2[h];
    float alpo = 0.f, bov = 0.f;
    if (h < DOUT) { alpo = expf(-1.0f / tau_m_o[h]); bov = b_o[h]; }

    float mem1 = 0.f, spk1 = 0.f, bb1v = BJ0;
    float mem2 = 0.f, spk2 = 0.f, bb2v = BJ0;
    float memo = 0.f;
    int n1p = 0, n2p = 0;

    float xp_cur = 0.f;
    if (half == 0) xp_cur = __builtin_nontemporal_load(XpB + h);
    __syncthreads();                       // staging complete (full drain, once)

    for (int i = 0; i <= TT + 1; ++i) {
        float xp_nxt = 0.f;
        if (half == 0 && i + 1 < TT)
            xp_nxt = __builtin_nontemporal_load(XpB + (size_t)(i + 1) * H1 + h);

        const bool dmo = (h < DOUT) && (i >= 2);

        // ---- gather phase (all 512 threads) ----
        int a110 = 0, a111 = 0, a112 = 0, a113 = 0;
        int a120 = 0, a121 = 0, a122 = 0, a123 = 0;
        int a220 = 0, a221 = 0, a222 = 0, a223 = 0;
        float ao0 = 0.f, ao1 = 0.f, ao2 = 0.f, ao3 = 0.f;

        const int ng1 = n1p >> 3;                       // multiple of 4
        for (int kk = 0; kk < ng1; kk += 4) {
            int4 e = *(const int4*)&lst1s[(g << 5) + kk];
            int4 pa = *(const int4*)(sP12 + ((size_t)e.x << 8) + l4);
            int4 pb = *(const int4*)(sP12 + ((size_t)e.y << 8) + l4);
            int4 pc = *(const int4*)(sP12 + ((size_t)e.z << 8) + l4);
            int4 pd = *(const int4*)(sP12 + ((size_t)e.w << 8) + l4);
            a110 += ((int)(short)pa.x + (int)(short)pb.x) + ((int)(short)pc.x + (int)(short)pd.x);
            a111 += ((int)(short)pa.y + (int)(short)pb.y) + ((int)(short)pc.y + (int)(short)pd.y);
            a112 += ((int)(short)pa.z + (int)(short)pb.z) + ((int)(short)pc.z + (int)(short)pd.z);
            a113 += ((int)(short)pa.w + (int)(short)pb.w) + ((int)(short)pc.w + (int)(short)pd.w);
            a120 += ((pa.x >> 16) + (pb.x >> 16)) + ((pc.x >> 16) + (pd.x >> 16));
            a121 += ((pa.y >> 16) + (pb.y >> 16)) + ((pc.y >> 16) + (pd.y >> 16));
            a122 += ((pa.z >> 16) + (pb.z >> 16)) + ((pc.z >> 16) + (pd.z >> 16));
            a123 += ((pa.w >> 16) + (pb.w >> 16)) + ((pc.w >> 16) + (pd.w >> 16));
        }
        const int ng2 = n2p >> 3;                       // multiple of 4
        for (int kk = 0; kk < ng2; kk += 4) {
            int4 e = *(const int4*)&lst2s[(g << 5) + kk];
            s16x4 wa = *(const s16x4*)(sT22L + (e.x << 8) + l4);
            s16x4 wb = *(const s16x4*)(sT22L + (e.y << 8) + l4);
            s16x4 wc = *(const s16x4*)(sT22L + (e.z << 8) + l4);
            s16x4 wd = *(const s16x4*)(sT22L + (e.w << 8) + l4);
            a220 += (wa.x + wb.x) + (wc.x + wd.x);
            a221 += (wa.y + wb.y) + (wc.y + wd.y);
            a222 += (wa.z + wb.z) + (wc.z + wd.z);
            a223 += (wa.w + wb.w) + (wc.w + wd.w);
            if (lane < 5) {
                float4 va = *(const float4*)(wT2o + e.x * DOUT + l4);
                float4 vb = *(const float4*)(wT2o + e.y * DOUT + l4);
                float4 vc = *(const float4*)(wT2o + e.z * DOUT + l4);
                float4 vd = *(const float4*)(wT2o + e.w * DOUT + l4);
                ao0 += (va.x + vb.x) + (vc.x + vd.x);
                ao1 += (va.y + vb.y) + (vc.y + vd.y);
                ao2 += (va.z + vb.z) + (vc.z + vd.z);
                ao3 += (va.w + vb.w) + (vc.w + vd.w);
            }
        }
        {
            int4 v;
            v.x = a110; v.y = a111; v.z = a112; v.w = a113;
            *(int4*)&pp11[g][l4] = v;
            v.x = a120; v.y = a121; v.z = a122; v.w = a123;
            *(int4*)&pp12[g][l4] = v;
            v.x = a220; v.y = a221; v.z = a222; v.w = a223;
            *(int4*)&pp22[g][l4] = v;
        }
        if (lane < 5) {
            float4 v; v.x = ao0; v.y = ao1; v.z = ao2; v.w = ao3;
            *(float4*)&pro[g][l4] = v;
        }
        BARRIER_LDS();                                 // B0: partials visible

        // ---- update phase (primary half only) ----
        unsigned long long m1 = 0, m2 = 0;
        float ns1 = 0.f, ns2 = 0.f;
        if (half == 0) {
            int ir11 = ((pp11[0][h] + pp11[1][h]) + (pp11[2][h] + pp11[3][h]))
                     + ((pp11[4][h] + pp11[5][h]) + (pp11[6][h] + pp11[7][h]));
            int ir12 = ((pp12[0][h] + pp12[1][h]) + (pp12[2][h] + pp12[3][h]))
                     + ((pp12[4][h] + pp12[5][h]) + (pp12[6][h] + pp12[7][h]));
            int ir22 = ((pp22[0][h] + pp22[1][h]) + (pp22[2][h] + pp22[3][h]))
                     + ((pp22[4][h] + pp22[5][h]) + (pp22[6][h] + pp22[7][h]));
            if (i < TT) {
                float r1 = (float)ir11 * IQSCALE;
                bb1v = ro1 * bb1v + BETAC * (1.f - ro1) * spk1;
                mem1 = mem1 * alpha1 - bb1v * spk1 + (1.f - alpha1) * (xp_cur + r1);
                ns1 = (mem1 - bb1v - BJ0) > 0.f ? 1.f : 0.f;
                spk1 = ns1;
                m1 = __ballot(ns1 != 0.f ? 1 : 0);
                if (lane == 0) wm1[wvp] = m1;
            }
            if (i >= 1 && i <= TT) {
                float r23 = (float)(ir22 + ir12) * IQSCALE;
                bb2v = ro2 * bb2v + BETAC * (1.f - ro2) * spk2;
                mem2 = mem2 * alpha2 - bb2v * spk2 + (1.f - alpha2) * (bh2v + r23);
                ns2 = (mem2 - bb2v - BJ0) > 0.f ? 1.f : 0.f;
                spk2 = ns2;
                m2 = __ballot(ns2 != 0.f ? 1 : 0);
                if (lane == 0) wm2[wvp] = m2;
            }
            if (dmo) {
                float ro = ((pro[0][h] + pro[1][h]) + (pro[2][h] + pro[3][h]))
                         + ((pro[4][h] + pro[5][h]) + (pro[6][h] + pro[7][h]));
                memo = memo * alpo + (1.f - alpo) * (bov + ro);
                __builtin_nontemporal_store(memo, MoB + (size_t)(i - 2) * DOUT + h);
            }
        }
        BARRIER_LDS();                                 // B1

        // ---- rebuild lst1 <- spk1(i), segmented: pos p -> seg p&7 slot p>>3
        if (i < TT) {
            unsigned long long q0 = wm1[0], q1 = wm1[1], q2 = wm1[2], q3 = wm1[3];
            int tot = (__popcll(q0) + __popcll(q1)) + (__popcll(q2) + __popcll(q3));
            if (half == 0) {
                int pos = __popcll(m1 & ((1ull << lane) - 1ull));
                if (wvp > 0) pos += __popcll(q0);
                if (wvp > 1) pos += __popcll(q1);
                if (wvp > 2) pos += __popcll(q2);
                if (ns1 != 0.f) lst1s[((pos & 7) << 5) + (pos >> 3)] = h;
                int np = (tot + 31) & ~31;
                if (h < np - tot) {
                    int p2 = tot + h;
                    lst1s[((p2 & 7) << 5) + (p2 >> 3)] = DUMMY;
                }
            }
            n1p = (tot + 31) & ~31;
        } else {
            n1p = 0;
        }
        // ---- rebuild lst2 <- spk2(i-1) ----
        if (i >= 1 && i <= TT) {
            unsigned long long q0 = wm2[0], q1 = wm2[1], q2 = wm2[2], q3 = wm2[3];
            int tot = (__popcll(q0) + __popcll(q1)) + (__popcll(q2) + __popcll(q3));
            if (half == 0) {
                int pos = __popcll(m2 & ((1ull << lane) - 1ull));
                if (wvp > 0) pos += __popcll(q0);
                if (wvp > 1) pos += __popcll(q1);
                if (wvp > 2) pos += __popcll(q2);
                if (ns2 != 0.f) lst2s[((pos & 7) << 5) + (pos >> 3)] = h;
                int np = (tot + 31) & ~31;
                if (h < np - tot) {
                    int p2 = tot + h;
                    lst2s[((p2 & 7) << 5) + (p2 >> 3)] = DUMMY;
                }
            }
            n2p = (tot + 31) & ~31;
        }
        BARRIER_LDS();                                 // B2

        xp_cur = xp_nxt;
    }
}

// ---------------------------------------------------------------------------
// soft_k: out[b][h] = Σ_t softmax(Mo[b][t])[h].  Fully parallel: one thread
// per timestep row (20-wide softmax), then a 20-lane reduction over t.
// ---------------------------------------------------------------------------
__global__ __launch_bounds__(256) void soft_k(const float* __restrict__ Mo,
                                              float* __restrict__ out) {
    const int b = blockIdx.x;
    const int t = threadIdx.x;
    __shared__ float sm[TT][DOUT];   // 250*20 floats = 20 KB... (80 KB bytes? 20000*4 = 80 KB)

    if (t < TT) {
        const float* row = Mo + ((size_t)b * TT + t) * DOUT;
        float v[DOUT];
        #pragma unroll
        for (int k = 0; k < DOUT; k += 4) {
            float4 r = *(const float4*)(row + k);
            v[k] = r.x; v[k + 1] = r.y; v[k + 2] = r.z; v[k + 3] = r.w;
        }
        float mx = v[0];
        #pragma unroll
        for (int j = 1; j < DOUT; ++j) mx = fmaxf(mx, v[j]);
        float s = 0.f;
        #pragma unroll
        for (int j = 0; j < DOUT; ++j) { v[j] = __expf(v[j] - mx); s += v[j]; }
        float inv = 1.0f / s;
        #pragma unroll
        for (int j = 0; j < DOUT; ++j) sm[t][j] = v[j] * inv;
    }
    __syncthreads();
    if (t < DOUT) {
        float acc = 0.f;
        for (int tt = 0; tt < TT; ++tt) acc += sm[tt][t];
        out[b * DOUT + t] = acc;
    }
}

extern "C" void kernel_launch(void* const* d_in, const int* in_sizes, int n_in,
                              void* d_out, int out_size, void* d_ws, size_t ws_size,
                              hipStream_t stream) {
    const float* x          = (const float*)d_in[0];
    const float* w_i2h1     = (const float*)d_in[1];
    const float* w_h12h1    = (const float*)d_in[2];
    const float* w_h12h2    = (const float*)d_in[3];
    const float* w_h22h2    = (const float*)d_in[4];
    const float* w_h2o      = (const float*)d_in[5];
    const float* b_h1       = (const float*)d_in[6];
    const float* b_h2       = (const float*)d_in[7];
    const float* b_o        = (const float*)d_in[8];
    const float* tau_adp_h1 = (const float*)d_in[9];
    const float* tau_adp_h2 = (const float*)d_in[10];
    const float* tau_m_h1   = (const float*)d_in[11];
    const float* tau_m_h2   = (const float*)d_in[12];
    const float* tau_m_o    = (const float*)d_in[13];

    short* sws = (short*)d_ws;
    float* fws = (float*)d_ws;
    const short* sT1  = sws;
    const int*   sP12 = (const int*)d_ws + IOFF_P12;
    const short* sT22 = sws + SOFF_T22;
    float* wT2o = fws + FOFF_W2O;
    float* Xp   = fws + FOFF_XP;
    float* Mo   = fws + FOFF_MO;

    transpose_all_k<<<(N_TRANS + 255) / 256, 256, 0, stream>>>(
        w_i2h1, w_h12h1, w_h12h2, w_h22h2, w_h2o, sws, fws);

    xproj_k<<<(BB * TT) / 4, 256, 0, stream>>>(x, sT1, b_h1, Xp);

    rec_k<<<BB, 512, 0, stream>>>(Xp, sP12, sT22, wT2o,
                                  b_h2, b_o, tau_adp_h1, tau_adp_h2,
                                  tau_m_h1, tau_m_h2, tau_m_o, Mo);

    soft_k<<<BB, 256, 0, stream>>>(Mo, (float*)d_out);
}

// Round 3
// 797.811 us; speedup vs baseline: 1.2367x; 1.1243x over previous
//
#include <hip/hip_runtime.h>
#include <cstdint>
#include <cstddef>

#define BB 256
#define TT 250
#define DIN 700
#define H1 256
#define H2 256
#define DOUT 20
#define BJ0 0.01f
#define BETAC 1.8f
#define DUMMY 256                 // zero row index in every padded table
#define IQSCALE 3.814697265625e-06f   // 2^-18

typedef float f32x4 __attribute__((ext_vector_type(4)));
typedef short s16x4 __attribute__((ext_vector_type(4)));

// ---------------------------------------------------------------------------
// Workspace layout:
//   sT1  [701*256] shorts @ s0        (row 700 = zeros)           bytes [0,358912)
//   sP12 [257*256] ints   @ i89728    lo=w_h12h1, hi=w_h12h2 q18  bytes [358912,622080)
//   sT22 [257*256] shorts @ s311040   (row 256 = zeros)           bytes [622080,753664)
//   wT2o [257*20]  floats @ f188416   (row 256 = zeros)
//   Xp   [256*250*256] floats @ f193556
//   Mo   [256*250*20]  floats @ f16577556   (per-step output membrane)
// ---------------------------------------------------------------------------
#define IOFF_P12 89728
#define SOFF_T22 311040
#define FOFF_W2O 188416
#define FOFF_XP  193556
#define FOFF_MO  16577556
#define N_TRANS  316180

// LDS-only drain + raw barrier: cross-thread data in rec_k flows exclusively
// through LDS, so we need not drain vmcnt (global loads stay in flight across
// the barrier — Xp prefetch and Mo stores span iterations).
#define BARRIER_LDS() asm volatile("s_waitcnt lgkmcnt(0)\n\ts_barrier" ::: "memory")

__device__ __forceinline__ short q18(float w) {
    float s = w * 262144.0f;
    s = fminf(fmaxf(s, -32767.0f), 32767.0f);
    return (short)__float2int_rn(s);
}

__global__ void transpose_all_k(const float* __restrict__ w_i2h1,
                                const float* __restrict__ w_h12h1,
                                const float* __restrict__ w_h12h2,
                                const float* __restrict__ w_h22h2,
                                const float* __restrict__ w_h2o,
                                short* __restrict__ sws,
                                float* __restrict__ fws) {
    int i = blockIdx.x * blockDim.x + threadIdx.x;
    if (i < 179456) { int d = i >> 8, h = i & 255;
        sws[i] = q18((d < DIN) ? w_i2h1[h * DIN + d] : 0.f); return; }
    i -= 179456;
    if (i < 65792) { int d = i >> 8, h = i & 255;
        unsigned int lo = 0, hi = 0;
        if (d < H1) {
            lo = (unsigned short)q18(w_h12h1[h * H1 + d]);
            hi = (unsigned short)q18(w_h12h2[h * H1 + d]);
        }
        ((int*)sws)[IOFF_P12 + i] = (int)(lo | (hi << 16)); return; }
    i -= 65792;
    if (i < 65792) { int d = i >> 8, h = i & 255;
        sws[SOFF_T22 + i] = q18((d < H2) ? w_h22h2[h * H2 + d] : 0.f); return; }
    i -= 65792;
    if (i < 5140)  { int j = i / 20, h = i % 20;
        fws[FOFF_W2O + i] = (j < H2) ? w_h2o[h * H2 + j] : 0.f; return; }
}

// ---------------------------------------------------------------------------
// Xp[b][t][h] = b_h1[h] + (Σ_{d active} sT1[d*256+h]) * 2^-18
// ---------------------------------------------------------------------------
__global__ __launch_bounds__(256) void xproj_k(const float* __restrict__ x,
                                               const short* __restrict__ sT1,
                                               const float* __restrict__ b_h1,
                                               float* __restrict__ Xp) {
    const int lane = threadIdx.x & 63;
    const int wv   = threadIdx.x >> 6;
    const int bt   = blockIdx.x * 4 + wv;   // grid = B*T/4 = 16000
    const int b    = bt / TT;
    const int t    = bt - b * TT;

    __shared__ __align__(16) int lst[4][712];

    const float* xrow = x + ((size_t)b * TT + t) * DIN;
    float xv[11];
    #pragma unroll
    for (int c = 0; c < 11; ++c) {
        int d = c * 64 + lane;
        xv[c] = (d < DIN) ? __builtin_nontemporal_load(xrow + d) : 0.f;
    }
    int cnt = 0;
    #pragma unroll
    for (int c = 0; c < 11; ++c) {
        int d = c * 64 + lane;
        bool p = (xv[c] != 0.0f);
        unsigned long long m = __ballot(p ? 1 : 0);
        if (p) {
            int pos = cnt + __popcll(m & ((1ull << lane) - 1ull));
            lst[wv][pos] = d;
        }
        cnt += __popcll(m);
    }
    int cntp = (cnt + 15) & ~15;
    if (lane < cntp - cnt) lst[wv][cnt + lane] = DIN;   // zero row pad
    __syncthreads();

    const int lo = lane * 4;
    int i0 = 0, i1 = 0, i2 = 0, i3 = 0;
    int j0 = 0, j1 = 0, j2 = 0, j3 = 0;
    for (int k = 0; k < cntp; k += 16) {
        int4 ja = *(const int4*)&lst[wv][k];
        int4 jb = *(const int4*)&lst[wv][k + 4];
        int4 jc = *(const int4*)&lst[wv][k + 8];
        int4 jd = *(const int4*)&lst[wv][k + 12];
        s16x4 w0  = *(const s16x4*)(sT1 + ((size_t)ja.x << 8) + lo);
        s16x4 w1  = *(const s16x4*)(sT1 + ((size_t)ja.y << 8) + lo);
        s16x4 w2  = *(const s16x4*)(sT1 + ((size_t)ja.z << 8) + lo);
        s16x4 w3  = *(const s16x4*)(sT1 + ((size_t)ja.w << 8) + lo);
        s16x4 w4  = *(const s16x4*)(sT1 + ((size_t)jb.x << 8) + lo);
        s16x4 w5  = *(const s16x4*)(sT1 + ((size_t)jb.y << 8) + lo);
        s16x4 w6  = *(const s16x4*)(sT1 + ((size_t)jb.z << 8) + lo);
        s16x4 w7  = *(const s16x4*)(sT1 + ((size_t)jb.w << 8) + lo);
        s16x4 w8  = *(const s16x4*)(sT1 + ((size_t)jc.x << 8) + lo);
        s16x4 w9  = *(const s16x4*)(sT1 + ((size_t)jc.y << 8) + lo);
        s16x4 w10 = *(const s16x4*)(sT1 + ((size_t)jc.z << 8) + lo);
        s16x4 w11 = *(const s16x4*)(sT1 + ((size_t)jc.w << 8) + lo);
        s16x4 w12 = *(const s16x4*)(sT1 + ((size_t)jd.x << 8) + lo);
        s16x4 w13 = *(const s16x4*)(sT1 + ((size_t)jd.y << 8) + lo);
        s16x4 w14 = *(const s16x4*)(sT1 + ((size_t)jd.z << 8) + lo);
        s16x4 w15 = *(const s16x4*)(sT1 + ((size_t)jd.w << 8) + lo);
        i0 += ((w0.x + w1.x) + (w2.x + w3.x)) + ((w4.x + w5.x) + (w6.x + w7.x));
        i1 += ((w0.y + w1.y) + (w2.y + w3.y)) + ((w4.y + w5.y) + (w6.y + w7.y));
        i2 += ((w0.z + w1.z) + (w2.z + w3.z)) + ((w4.z + w5.z) + (w6.z + w7.z));
        i3 += ((w0.w + w1.w) + (w2.w + w3.w)) + ((w4.w + w5.w) + (w6.w + w7.w));
        j0 += ((w8.x + w9.x) + (w10.x + w11.x)) + ((w12.x + w13.x) + (w14.x + w15.x));
        j1 += ((w8.y + w9.y) + (w10.y + w11.y)) + ((w12.y + w13.y) + (w14.y + w15.y));
        j2 += ((w8.z + w9.z) + (w10.z + w11.z)) + ((w12.z + w13.z) + (w14.z + w15.z));
        j3 += ((w8.w + w9.w) + (w10.w + w11.w)) + ((w12.w + w13.w) + (w14.w + w15.w));
    }
    f32x4 acc = *(const f32x4*)(b_h1 + lo);
    acc.x += (float)(i0 + j0) * IQSCALE;
    acc.y += (float)(i1 + j1) * IQSCALE;
    acc.z += (float)(i2 + j2) * IQSCALE;
    acc.w += (float)(i3 + j3) * IQSCALE;
    __builtin_nontemporal_store(acc, (f32x4*)(Xp + ((size_t)b * TT + t) * H1 + lo));
}

// ---------------------------------------------------------------------------
// rec_k: 512 threads = 8 gather groups of 64 lanes. 2 barriers/iteration.
//   Lists are DOUBLE-BUFFERED and ATOMIC-COMPACTED:
//     - gather phase: each thread DUMMY-fills one slot of the NEXT buffer
//       (pre-padding), tid 0/256 zero the next counters.
//     - update phase: primary waves run U1 (layer 1), secondary waves run
//       U2 + memo (layer 2 / output). Each wave ballots its own 64 neurons,
//       lane0 atomicAdd's the next-buffer count, __shfl-broadcasts the base,
//       spiking lanes scatter h into slot ((pos&7)<<5)+(pos>>3) directly.
//   No wm mask exchange, no rebuild phase, no B1.
//   Integer gather sums are order-independent => spike path stays exact.
// LDS: 131584 + 2*2048 + 3*8192 + 640 + 16 = 160,912 B (1 block/CU).
// ---------------------------------------------------------------------------
__global__ __launch_bounds__(512) void rec_k(
    const float* __restrict__ Xp,
    const int*   __restrict__ sP12,
    const short* __restrict__ sT22, const float* __restrict__ wT2o,
    const float* __restrict__ b_h2, const float* __restrict__ b_o,
    const float* __restrict__ tau_adp_h1, const float* __restrict__ tau_adp_h2,
    const float* __restrict__ tau_m_h1, const float* __restrict__ tau_m_h2,
    const float* __restrict__ tau_m_o,
    float* __restrict__ Mo) {
    const int tid  = threadIdx.x;        // 0..511
    const int h    = tid & 255;
    const int half = tid >> 8;           // 0 = layer1 (U1), 1 = layer2 (U2+out)
    const int lane = tid & 63;
    const int g    = tid >> 6;           // gather group 0..7
    const int l4   = lane << 2;          // 4-column base
    const int b    = blockIdx.x;
    const float* __restrict__ XpB = Xp + (size_t)b * TT * H1;
    float* __restrict__ MoB = Mo + (size_t)b * TT * DOUT;

    __shared__ __align__(16) short sT22L[65792];   // 257*256 int16 = 128.5 KB
    __shared__ __align__(16) int lst1s[2][256];    // dbuf: 8 segments x 32 slots
    __shared__ __align__(16) int lst2s[2][256];
    __shared__ __align__(16) int lcnt[2][2];       // [buf][layer]
    __shared__ __align__(16) int pp11[8][256];
    __shared__ __align__(16) int pp12[8][256];
    __shared__ __align__(16) int pp22[8][256];
    __shared__ __align__(16) float pro[8][20];

    // one-time staging: sT22 (dword copy) + counter init
    {
        const int* src = (const int*)sT22;
        int* dst = (int*)sT22L;
        for (int i2 = tid; i2 < 32896; i2 += 512) dst[i2] = src[i2];
        if (tid < 4) lcnt[tid >> 1][tid & 1] = 0;
    }

    const float alpha1 = expf(-1.0f / tau_m_h1[h]);
    const float ro1    = expf(-1.0f / tau_adp_h1[h]);
    const float alpha2 = expf(-1.0f / tau_m_h2[h]);
    const float ro2    = expf(-1.0f / tau_adp_h2[h]);
    const float bh2v   = b_h2[h];
    float alpo = 0.f, bov = 0.f;
    if (h < DOUT) { alpo = expf(-1.0f / tau_m_o[h]); bov = b_o[h]; }

    // layer state lives in the owning half's registers
    float mem1 = 0.f, spk1 = 0.f, bb1v = BJ0;     // primary half
    float mem2 = 0.f, spk2 = 0.f, bb2v = BJ0;     // secondary half
    float memo = 0.f;                             // secondary h<20

    float xp_cur = 0.f;
    if (half == 0) xp_cur = __builtin_nontemporal_load(XpB + h);
    __syncthreads();                       // staging complete (full drain, once)

    for (int i = 0; i <= TT + 1; ++i) {
        const int cur = i & 1, nxt = cur ^ 1;

        float xp_nxt = 0.f;
        if (half == 0 && i + 1 < TT)
            xp_nxt = __builtin_nontemporal_load(XpB + (size_t)(i + 1) * H1 + h);

        // ---- counts for this iteration's gather ----
        const int tot1 = lcnt[cur][0];
        const int tot2 = lcnt[cur][1];
        const int n1p = (tot1 + 31) & ~31;
        const int n2p = (tot2 + 31) & ~31;

        // ---- pre-pad NEXT list buffer + zero next counters ----
        if (half == 0) lst1s[nxt][h] = DUMMY; else lst2s[nxt][h] = DUMMY;
        if (tid == 0)   lcnt[nxt][0] = 0;
        if (tid == 256) lcnt[nxt][1] = 0;

        // ---- gather phase (all 512 threads) ----
        int a110 = 0, a111 = 0, a112 = 0, a113 = 0;
        int a120 = 0, a121 = 0, a122 = 0, a123 = 0;
        int a220 = 0, a221 = 0, a222 = 0, a223 = 0;
        float ao0 = 0.f, ao1 = 0.f, ao2 = 0.f, ao3 = 0.f;

        const int gbase = g << 5;
        const int ng1 = n1p >> 3;                       // multiple of 4
        for (int kk = 0; kk < ng1; kk += 4) {
            int4 e = *(const int4*)&lst1s[cur][gbase + kk];
            int4 pa = *(const int4*)(sP12 + ((size_t)e.x << 8) + l4);
            int4 pb = *(const int4*)(sP12 + ((size_t)e.y << 8) + l4);
            int4 pc = *(const int4*)(sP12 + ((size_t)e.z << 8) + l4);
            int4 pd = *(const int4*)(sP12 + ((size_t)e.w << 8) + l4);
            a110 += ((int)(short)pa.x + (int)(short)pb.x) + ((int)(short)pc.x + (int)(short)pd.x);
            a111 += ((int)(short)pa.y + (int)(short)pb.y) + ((int)(short)pc.y + (int)(short)pd.y);
            a112 += ((int)(short)pa.z + (int)(short)pb.z) + ((int)(short)pc.z + (int)(short)pd.z);
            a113 += ((int)(short)pa.w + (int)(short)pb.w) + ((int)(short)pc.w + (int)(short)pd.w);
            a120 += ((pa.x >> 16) + (pb.x >> 16)) + ((pc.x >> 16) + (pd.x >> 16));
            a121 += ((pa.y >> 16) + (pb.y >> 16)) + ((pc.y >> 16) + (pd.y >> 16));
            a122 += ((pa.z >> 16) + (pb.z >> 16)) + ((pc.z >> 16) + (pd.z >> 16));
            a123 += ((pa.w >> 16) + (pb.w >> 16)) + ((pc.w >> 16) + (pd.w >> 16));
        }
        const int ng2 = n2p >> 3;                       // multiple of 4
        for (int kk = 0; kk < ng2; kk += 4) {
            int4 e = *(const int4*)&lst2s[cur][gbase + kk];
            s16x4 wa = *(const s16x4*)(sT22L + (e.x << 8) + l4);
            s16x4 wb = *(const s16x4*)(sT22L + (e.y << 8) + l4);
            s16x4 wc = *(const s16x4*)(sT22L + (e.z << 8) + l4);
            s16x4 wd = *(const s16x4*)(sT22L + (e.w << 8) + l4);
            a220 += (wa.x + wb.x) + (wc.x + wd.x);
            a221 += (wa.y + wb.y) + (wc.y + wd.y);
            a222 += (wa.z + wb.z) + (wc.z + wd.z);
            a223 += (wa.w + wb.w) + (wc.w + wd.w);
            if (lane < 5) {
                float4 va = *(const float4*)(wT2o + e.x * DOUT + l4);
                float4 vb = *(const float4*)(wT2o + e.y * DOUT + l4);
                float4 vc = *(const float4*)(wT2o + e.z * DOUT + l4);
                float4 vd = *(const float4*)(wT2o + e.w * DOUT + l4);
                ao0 += (va.x + vb.x) + (vc.x + vd.x);
                ao1 += (va.y + vb.y) + (vc.y + vd.y);
                ao2 += (va.z + vb.z) + (vc.z + vd.z);
                ao3 += (va.w + vb.w) + (vc.w + vd.w);
            }
        }
        {
            int4 v;
            v.x = a110; v.y = a111; v.z = a112; v.w = a113;
            *(int4*)&pp11[g][l4] = v;
            v.x = a120; v.y = a121; v.z = a122; v.w = a123;
            *(int4*)&pp12[g][l4] = v;
            v.x = a220; v.y = a221; v.z = a222; v.w = a223;
            *(int4*)&pp22[g][l4] = v;
        }
        if (lane < 5) {
            float4 v; v.x = ao0; v.y = ao1; v.z = ao2; v.w = ao3;
            *(float4*)&pro[g][l4] = v;
        }
        BARRIER_LDS();                                 // B0: partials + pads visible

        // ---- update phase: U1 on primary waves, U2+output on secondary ----
        if (half == 0) {
            if (i < TT) {
                int ir11 = ((pp11[0][h] + pp11[1][h]) + (pp11[2][h] + pp11[3][h]))
                         + ((pp11[4][h] + pp11[5][h]) + (pp11[6][h] + pp11[7][h]));
                float r1 = (float)ir11 * IQSCALE;
                bb1v = ro1 * bb1v + BETAC * (1.f - ro1) * spk1;
                mem1 = mem1 * alpha1 - bb1v * spk1 + (1.f - alpha1) * (xp_cur + r1);
                float ns1 = (mem1 - bb1v - BJ0) > 0.f ? 1.f : 0.f;
                spk1 = ns1;
                unsigned long long m1 = __ballot(ns1 != 0.f ? 1 : 0);
                int c = __popcll(m1);
                int base = 0;
                if (lane == 0) base = atomicAdd(&lcnt[nxt][0], c);
                base = __shfl(base, 0);
                if (ns1 != 0.f) {
                    int pos = base + __popcll(m1 & ((1ull << lane) - 1ull));
                    lst1s[nxt][((pos & 7) << 5) + (pos >> 3)] = h;
                }
            }
        } else {
            if (i >= 1 && i <= TT) {
                int ir12 = ((pp12[0][h] + pp12[1][h]) + (pp12[2][h] + pp12[3][h]))
                         + ((pp12[4][h] + pp12[5][h]) + (pp12[6][h] + pp12[7][h]));
                int ir22 = ((pp22[0][h] + pp22[1][h]) + (pp22[2][h] + pp22[3][h]))
                         + ((pp22[4][h] + pp22[5][h]) + (pp22[6][h] + pp22[7][h]));
                float r23 = (float)(ir22 + ir12) * IQSCALE;
                bb2v = ro2 * bb2v + BETAC * (1.f - ro2) * spk2;
                mem2 = mem2 * alpha2 - bb2v * spk2 + (1.f - alpha2) * (bh2v + r23);
                float ns2 = (mem2 - bb2v - BJ0) > 0.f ? 1.f : 0.f;
                spk2 = ns2;
                unsigned long long m2 = __ballot(ns2 != 0.f ? 1 : 0);
                int c = __popcll(m2);
                int base = 0;
                if (lane == 0) base = atomicAdd(&lcnt[nxt][1], c);
                base = __shfl(base, 0);
                if (ns2 != 0.f) {
                    int pos = base + __popcll(m2 & ((1ull << lane) - 1ull));
                    lst2s[nxt][((pos & 7) << 5) + (pos >> 3)] = h;
                }
            }
            if ((h < DOUT) && (i >= 2)) {
                float ro = ((pro[0][h] + pro[1][h]) + (pro[2][h] + pro[3][h]))
                         + ((pro[4][h] + pro[5][h]) + (pro[6][h] + pro[7][h]));
                memo = memo * alpo + (1.f - alpo) * (bov + ro);
                __builtin_nontemporal_store(memo, MoB + (size_t)(i - 2) * DOUT + h);
            }
        }
        BARRIER_LDS();                                 // B2: lists ready

        xp_cur = xp_nxt;
    }
}

// ---------------------------------------------------------------------------
// soft_k: out[b][h] = Σ_t softmax(Mo[b][t])[h].  One thread per timestep row.
// ---------------------------------------------------------------------------
__global__ __launch_bounds__(256) void soft_k(const float* __restrict__ Mo,
                                              float* __restrict__ out) {
    const int b = blockIdx.x;
    const int t = threadIdx.x;
    __shared__ float sm[TT][DOUT];

    if (t < TT) {
        const float* row = Mo + ((size_t)b * TT + t) * DOUT;
        float v[DOUT];
        #pragma unroll
        for (int k = 0; k < DOUT; k += 4) {
            float4 r = *(const float4*)(row + k);
            v[k] = r.x; v[k + 1] = r.y; v[k + 2] = r.z; v[k + 3] = r.w;
        }
        float mx = v[0];
        #pragma unroll
        for (int j = 1; j < DOUT; ++j) mx = fmaxf(mx, v[j]);
        float s = 0.f;
        #pragma unroll
        for (int j = 0; j < DOUT; ++j) { v[j] = __expf(v[j] - mx); s += v[j]; }
        float inv = 1.0f / s;
        #pragma unroll
        for (int j = 0; j < DOUT; ++j) sm[t][j] = v[j] * inv;
    }
    __syncthreads();
    if (t < DOUT) {
        float acc = 0.f;
        for (int tt = 0; tt < TT; ++tt) acc += sm[tt][t];
        out[b * DOUT + t] = acc;
    }
}

extern "C" void kernel_launch(void* const* d_in, const int* in_sizes, int n_in,
                              void* d_out, int out_size, void* d_ws, size_t ws_size,
                              hipStream_t stream) {
    const float* x          = (const float*)d_in[0];
    const float* w_i2h1     = (const float*)d_in[1];
    const float* w_h12h1    = (const float*)d_in[2];
    const float* w_h12h2    = (const float*)d_in[3];
    const float* w_h22h2    = (const float*)d_in[4];
    const float* w_h2o      = (const float*)d_in[5];
    const float* b_h1       = (const float*)d_in[6];
    const float* b_h2       = (const float*)d_in[7];
    const float* b_o        = (const float*)d_in[8];
    const float* tau_adp_h1 = (const float*)d_in[9];
    const float* tau_adp_h2 = (const float*)d_in[10];
    const float* tau_m_h1   = (const float*)d_in[11];
    const float* tau_m_h2   = (const float*)d_in[12];
    const float* tau_m_o    = (const float*)d_in[13];

    short* sws = (short*)d_ws;
    float* fws = (float*)d_ws;
    const short* sT1  = sws;
    const int*   sP12 = (const int*)d_ws + IOFF_P12;
    const short* sT22 = sws + SOFF_T22;
    float* wT2o = fws + FOFF_W2O;
    float* Xp   = fws + FOFF_XP;
    float* Mo   = fws + FOFF_MO;

    transpose_all_k<<<(N_TRANS + 255) / 256, 256, 0, stream>>>(
        w_i2h1, w_h12h1, w_h12h2, w_h22h2, w_h2o, sws, fws);

    xproj_k<<<(BB * TT) / 4, 256, 0, stream>>>(x, sT1, b_h1, Xp);

    rec_k<<<BB, 512, 0, stream>>>(Xp, sP12, sT22, wT2o,
                                  b_h2, b_o, tau_adp_h1, tau_adp_h2,
                                  tau_m_h1, tau_m_h2, tau_m_o, Mo);

    soft_k<<<BB, 256, 0, stream>>>(Mo, (float*)d_out);
}

// Round 4
// 753.841 us; speedup vs baseline: 1.3088x; 1.0583x over previous
//
#include <hip/hip_runtime.h>
#include <cstdint>
#include <cstddef>

#define BB 256
#define TT 250
#define DIN 700
#define H1 256
#define H2 256
#define DOUT 20
#define BJ0 0.01f
#define BETAC 1.8f
#define DUMMY 256                 // zero row index in every padded table
#define IQSCALE 3.814697265625e-06f   // 2^-18

typedef float f32x4 __attribute__((ext_vector_type(4)));
typedef short s16x4 __attribute__((ext_vector_type(4)));
typedef int   i32x4 __attribute__((ext_vector_type(4)));

// ---------------------------------------------------------------------------
// Workspace layout (bytes):
//   Bh   [256*704] i8  @ 0         hi8 of q18(w_i2h1), k-pad 700..703 = 0
//   Bl   [256*704] i8  @ 180224    lo8 (q = 256*hi + lo, exact)
//   sP12 [257*256] int @ 360448    lo=w_h12h1, hi=w_h12h2 q18 (row 256 = 0)
//   sT22 [257*256] s16 @ 623616    (row 256 = zeros)
//   wT2o [257*20]  f32 @ 755200    (row 256 = zeros)
//   Xp   [64000*256] f32 @ 775776
//   Mo   [256*250*20] f32 @ 66311776   (per-step output membrane)
// ---------------------------------------------------------------------------
#define COFF_BL  180224
#define IOFF_P12 90112
#define SOFF_T22 311808
#define FOFF_W2O 188800
#define FOFF_XP  193944
#define FOFF_MO  16577944
#define N_TRANS  316948

// LDS-only drain + raw barrier (rec_k): cross-thread data flows exclusively
// through LDS; global loads stay in flight across the barrier.
#define BARRIER_LDS() asm volatile("s_waitcnt lgkmcnt(0)\n\ts_barrier" ::: "memory")

__device__ __forceinline__ short q18(float w) {
    float s = w * 262144.0f;
    s = fminf(fmaxf(s, -32767.0f), 32767.0f);
    return (short)__float2int_rn(s);
}

__global__ void transpose_all_k(const float* __restrict__ w_i2h1,
                                const float* __restrict__ w_h12h1,
                                const float* __restrict__ w_h12h2,
                                const float* __restrict__ w_h22h2,
                                const float* __restrict__ w_h2o,
                                signed char* __restrict__ cws,
                                short* __restrict__ sws,
                                int* __restrict__ iws,
                                float* __restrict__ fws) {
    int i = blockIdx.x * blockDim.x + threadIdx.x;
    if (i < 180224) {               // Bh/Bl: [h=0..255][k=0..703]
        int h = i / 704, k = i - h * 704;
        int q = (k < DIN) ? (int)q18(w_i2h1[h * DIN + k]) : 0;
        q = q > 32639 ? 32639 : (q < -32640 ? -32640 : q);  // keep hi8 in range
        int hi = (q + 128) >> 8;
        int lo = q - (hi << 8);
        cws[i] = (signed char)hi;
        cws[COFF_BL + i] = (signed char)lo;
        return;
    }
    i -= 180224;
    if (i < 65792) { int d = i >> 8, h = i & 255;
        unsigned int lo = 0, hi = 0;
        if (d < H1) {
            lo = (unsigned short)q18(w_h12h1[h * H1 + d]);
            hi = (unsigned short)q18(w_h12h2[h * H1 + d]);
        }
        iws[IOFF_P12 + i] = (int)(lo | (hi << 16)); return; }
    i -= 65792;
    if (i < 65792) { int d = i >> 8, h = i & 255;
        sws[SOFF_T22 + i] = q18((d < H2) ? w_h22h2[h * H2 + d] : 0.f); return; }
    i -= 65792;
    if (i < 5140)  { int j = i / 20, h = i % 20;
        fws[FOFF_W2O + i] = (j < H2) ? w_h2o[h * H2 + j] : 0.f; return; }
}

// ---------------------------------------------------------------------------
// xgemm_k: Xp = x @ W^T + b_h1 via two exact i8 MFMA GEMMs.
//   q18 = 256*hi8 + lo8  =>  ir = 256*acc_hi + acc_lo  (bit-identical to the
//   previous int16 gather path, since x ∈ {0,1} is exact in i8).
// M=64000 (b*t), N=256, K=704. BM=32, BN=256, 2000 blocks x 256 threads.
// Wave w owns cols [64w,64w+64): 2 m-tiles x 4 n-tiles x {hi,lo} accs.
// LDS: A 32x720 (23.0K) + Bh/Bl 256x80 (20K each) = 64.0 KB -> 2 blocks/CU.
// Row pads (720/80 B) put consecutive rows 20 banks apart -> 2-way (free).
// ---------------------------------------------------------------------------
__global__ __launch_bounds__(256) void xgemm_k(const float* __restrict__ x,
                                               const signed char* __restrict__ Bh,
                                               const signed char* __restrict__ Bl,
                                               const float* __restrict__ b_h1,
                                               float* __restrict__ Xp) {
    const int t    = threadIdx.x;
    const int lane = t & 63;
    const int w    = t >> 6;             // wave 0..3 -> cols [64w, 64w+64)
    const int m0   = blockIdx.x * 32;

    __shared__ __align__(16) signed char Asub[32 * 720];
    __shared__ __align__(16) signed char Bhs[256 * 80];
    __shared__ __align__(16) signed char Bls[256 * 80];

    // ---- stage A: 32 rows x 704 k, fp32 -> i8 {0,1} (x is binary) ----
    // 32*176 float4 slots = 5632; 256 threads x 22 iterations.
    #pragma unroll
    for (int it = 0; it < 22; ++it) {
        int flat = it * 256 + t;
        int row  = flat / 176;
        int c4   = flat - row * 176;
        unsigned int pk = 0u;
        if (c4 < 175) {                  // c4==175 covers k=700..703 -> all pad
            const float* xr = x + (size_t)(m0 + row) * DIN;
            float4 f = *(const float4*)(xr + (c4 << 2));
            pk = (f.x != 0.f ? 1u : 0u)
               | (f.y != 0.f ? 1u : 0u) << 8
               | (f.z != 0.f ? 1u : 0u) << 16
               | (f.w != 0.f ? 1u : 0u) << 24;
        }
        *(unsigned int*)(Asub + row * 720 + (c4 << 2)) = pk;
    }

    i32x4 acch[2][4], accl[2][4];
    #pragma unroll
    for (int mt = 0; mt < 2; ++mt)
        #pragma unroll
        for (int nt = 0; nt < 4; ++nt) {
            acch[mt][nt] = (i32x4){0, 0, 0, 0};
            accl[mt][nt] = (i32x4){0, 0, 0, 0};
        }

    const int arow  = lane & 15;         // A row within tile / B,C col
    const int kg16  = (lane >> 4) << 4;  // k-group byte offset
    const int bcol0 = w << 6;

    for (int ks = 0; ks < 11; ++ks) {
        __syncthreads();                 // previous step's B reads complete
        // ---- stage Bh/Bl K-panel: 256 rows x 64 B (4 threads per row) ----
        #pragma unroll
        for (int it2 = 0; it2 < 4; ++it2) {
            int row = it2 * 64 + (t >> 2);
            int ch  = (t & 3) << 4;
            int go  = row * 704 + ks * 64 + ch;
            *(int4*)(Bhs + row * 80 + ch) = *(const int4*)(Bh + go);
            *(int4*)(Bls + row * 80 + ch) = *(const int4*)(Bl + go);
        }
        __syncthreads();                 // panel ready

        const int ko = ks * 64 + kg16;
        i32x4 a0 = *(const i32x4*)(Asub + arow * 720 + ko);
        i32x4 a1 = *(const i32x4*)(Asub + (16 + arow) * 720 + ko);
        #pragma unroll
        for (int nt = 0; nt < 4; ++nt) {
            const int bb = (bcol0 + nt * 16 + arow) * 80 + kg16;
            i32x4 bhf = *(const i32x4*)(Bhs + bb);
            i32x4 blf = *(const i32x4*)(Bls + bb);
            acch[0][nt] = __builtin_amdgcn_mfma_i32_16x16x64_i8(a0, bhf, acch[0][nt], 0, 0, 0);
            acch[1][nt] = __builtin_amdgcn_mfma_i32_16x16x64_i8(a1, bhf, acch[1][nt], 0, 0, 0);
            accl[0][nt] = __builtin_amdgcn_mfma_i32_16x16x64_i8(a0, blf, accl[0][nt], 0, 0, 0);
            accl[1][nt] = __builtin_amdgcn_mfma_i32_16x16x64_i8(a1, blf, accl[1][nt], 0, 0, 0);
        }
    }

    // ---- epilogue: ir = 256*hi + lo; Xp = b_h1 + ir * 2^-18 ----
    const int crb = (lane >> 4) << 2;    // C row base within tile
    #pragma unroll
    for (int nt = 0; nt < 4; ++nt) {
        int col = bcol0 + nt * 16 + arow;
        float bias = b_h1[col];
        #pragma unroll
        for (int mt = 0; mt < 2; ++mt) {
            #pragma unroll
            for (int r = 0; r < 4; ++r) {
                int row = m0 + mt * 16 + crb + r;
                int ir = (acch[mt][nt][r] << 8) + accl[mt][nt][r];
                __builtin_nontemporal_store(bias + (float)ir * IQSCALE,
                                            Xp + (size_t)row * H1 + col);
            }
        }
    }
}

// ---------------------------------------------------------------------------
// rec_k: unchanged from R3 (2 barriers/iter, atomic-compacted dbuf lists).
// ---------------------------------------------------------------------------
__global__ __launch_bounds__(512) void rec_k(
    const float* __restrict__ Xp,
    const int*   __restrict__ sP12,
    const short* __restrict__ sT22, const float* __restrict__ wT2o,
    const float* __restrict__ b_h2, const float* __restrict__ b_o,
    const float* __restrict__ tau_adp_h1, const float* __restrict__ tau_adp_h2,
    const float* __restrict__ tau_m_h1, const float* __restrict__ tau_m_h2,
    const float* __restrict__ tau_m_o,
    float* __restrict__ Mo) {
    const int tid  = threadIdx.x;        // 0..511
    const int h    = tid & 255;
    const int half = tid >> 8;           // 0 = layer1 (U1), 1 = layer2 (U2+out)
    const int lane = tid & 63;
    const int g    = tid >> 6;           // gather group 0..7
    const int l4   = lane << 2;          // 4-column base
    const int b    = blockIdx.x;
    const float* __restrict__ XpB = Xp + (size_t)b * TT * H1;
    float* __restrict__ MoB = Mo + (size_t)b * TT * DOUT;

    __shared__ __align__(16) short sT22L[65792];   // 257*256 int16 = 128.5 KB
    __shared__ __align__(16) int lst1s[2][256];    // dbuf: 8 segments x 32 slots
    __shared__ __align__(16) int lst2s[2][256];
    __shared__ __align__(16) int lcnt[2][2];       // [buf][layer]
    __shared__ __align__(16) int pp11[8][256];
    __shared__ __align__(16) int pp12[8][256];
    __shared__ __align__(16) int pp22[8][256];
    __shared__ __align__(16) float pro[8][20];

    // one-time staging: sT22 (dword copy) + counter init
    {
        const int* src = (const int*)sT22;
        int* dst = (int*)sT22L;
        for (int i2 = tid; i2 < 32896; i2 += 512) dst[i2] = src[i2];
        if (tid < 4) lcnt[tid >> 1][tid & 1] = 0;
    }

    const float alpha1 = expf(-1.0f / tau_m_h1[h]);
    const float ro1    = expf(-1.0f / tau_adp_h1[h]);
    const float alpha2 = expf(-1.0f / tau_m_h2[h]);
    const float ro2    = expf(-1.0f / tau_adp_h2[h]);
    const float bh2v   = b_h2[h];
    float alpo = 0.f, bov = 0.f;
    if (h < DOUT) { alpo = expf(-1.0f / tau_m_o[h]); bov = b_o[h]; }

    float mem1 = 0.f, spk1 = 0.f, bb1v = BJ0;     // primary half
    float mem2 = 0.f, spk2 = 0.f, bb2v = BJ0;     // secondary half
    float memo = 0.f;                             // secondary h<20

    float xp_cur = 0.f;
    if (half == 0) xp_cur = __builtin_nontemporal_load(XpB + h);
    __syncthreads();                       // staging complete (full drain, once)

    for (int i = 0; i <= TT + 1; ++i) {
        const int cur = i & 1, nxt = cur ^ 1;

        float xp_nxt = 0.f;
        if (half == 0 && i + 1 < TT)
            xp_nxt = __builtin_nontemporal_load(XpB + (size_t)(i + 1) * H1 + h);

        const int tot1 = lcnt[cur][0];
        const int tot2 = lcnt[cur][1];
        const int n1p = (tot1 + 31) & ~31;
        const int n2p = (tot2 + 31) & ~31;

        // ---- pre-pad NEXT list buffer + zero next counters ----
        if (half == 0) lst1s[nxt][h] = DUMMY; else lst2s[nxt][h] = DUMMY;
        if (tid == 0)   lcnt[nxt][0] = 0;
        if (tid == 256) lcnt[nxt][1] = 0;

        // ---- gather phase (all 512 threads) ----
        int a110 = 0, a111 = 0, a112 = 0, a113 = 0;
        int a120 = 0, a121 = 0, a122 = 0, a123 = 0;
        int a220 = 0, a221 = 0, a222 = 0, a223 = 0;
        float ao0 = 0.f, ao1 = 0.f, ao2 = 0.f, ao3 = 0.f;

        const int gbase = g << 5;
        const int ng1 = n1p >> 3;
        for (int kk = 0; kk < ng1; kk += 4) {
            int4 e = *(const int4*)&lst1s[cur][gbase + kk];
            int4 pa = *(const int4*)(sP12 + ((size_t)e.x << 8) + l4);
            int4 pb = *(const int4*)(sP12 + ((size_t)e.y << 8) + l4);
            int4 pc = *(const int4*)(sP12 + ((size_t)e.z << 8) + l4);
            int4 pd = *(const int4*)(sP12 + ((size_t)e.w << 8) + l4);
            a110 += ((int)(short)pa.x + (int)(short)pb.x) + ((int)(short)pc.x + (int)(short)pd.x);
            a111 += ((int)(short)pa.y + (int)(short)pb.y) + ((int)(short)pc.y + (int)(short)pd.y);
            a112 += ((int)(short)pa.z + (int)(short)pb.z) + ((int)(short)pc.z + (int)(short)pd.z);
            a113 += ((int)(short)pa.w + (int)(short)pb.w) + ((int)(short)pc.w + (int)(short)pd.w);
            a120 += ((pa.x >> 16) + (pb.x >> 16)) + ((pc.x >> 16) + (pd.x >> 16));
            a121 += ((pa.y >> 16) + (pb.y >> 16)) + ((pc.y >> 16) + (pd.y >> 16));
            a122 += ((pa.z >> 16) + (pb.z >> 16)) + ((pc.z >> 16) + (pd.z >> 16));
            a123 += ((pa.w >> 16) + (pb.w >> 16)) + ((pc.w >> 16) + (pd.w >> 16));
        }
        const int ng2 = n2p >> 3;
        for (int kk = 0; kk < ng2; kk += 4) {
            int4 e = *(const int4*)&lst2s[cur][gbase + kk];
            s16x4 wa = *(const s16x4*)(sT22L + (e.x << 8) + l4);
            s16x4 wb = *(const s16x4*)(sT22L + (e.y << 8) + l4);
            s16x4 wc = *(const s16x4*)(sT22L + (e.z << 8) + l4);
            s16x4 wd = *(const s16x4*)(sT22L + (e.w << 8) + l4);
            a220 += (wa.x + wb.x) + (wc.x + wd.x);
            a221 += (wa.y + wb.y) + (wc.y + wd.y);
            a222 += (wa.z + wb.z) + (wc.z + wd.z);
            a223 += (wa.w + wb.w) + (wc.w + wd.w);
            if (lane < 5) {
                float4 va = *(const float4*)(wT2o + e.x * DOUT + l4);
                float4 vb = *(const float4*)(wT2o + e.y * DOUT + l4);
                float4 vc = *(const float4*)(wT2o + e.z * DOUT + l4);
                float4 vd = *(const float4*)(wT2o + e.w * DOUT + l4);
                ao0 += (va.x + vb.x) + (vc.x + vd.x);
                ao1 += (va.y + vb.y) + (vc.y + vd.y);
                ao2 += (va.z + vb.z) + (vc.z + vd.z);
                ao3 += (va.w + vb.w) + (vc.w + vd.w);
            }
        }
        {
            int4 v;
            v.x = a110; v.y = a111; v.z = a112; v.w = a113;
            *(int4*)&pp11[g][l4] = v;
            v.x = a120; v.y = a121; v.z = a122; v.w = a123;
            *(int4*)&pp12[g][l4] = v;
            v.x = a220; v.y = a221; v.z = a222; v.w = a223;
            *(int4*)&pp22[g][l4] = v;
        }
        if (lane < 5) {
            float4 v; v.x = ao0; v.y = ao1; v.z = ao2; v.w = ao3;
            *(float4*)&pro[g][l4] = v;
        }
        BARRIER_LDS();                                 // B0

        // ---- update phase: U1 on primary waves, U2+output on secondary ----
        if (half == 0) {
            if (i < TT) {
                int ir11 = ((pp11[0][h] + pp11[1][h]) + (pp11[2][h] + pp11[3][h]))
                         + ((pp11[4][h] + pp11[5][h]) + (pp11[6][h] + pp11[7][h]));
                float r1 = (float)ir11 * IQSCALE;
                bb1v = ro1 * bb1v + BETAC * (1.f - ro1) * spk1;
                mem1 = mem1 * alpha1 - bb1v * spk1 + (1.f - alpha1) * (xp_cur + r1);
                float ns1 = (mem1 - bb1v - BJ0) > 0.f ? 1.f : 0.f;
                spk1 = ns1;
                unsigned long long m1 = __ballot(ns1 != 0.f ? 1 : 0);
                int c = __popcll(m1);
                int base = 0;
                if (lane == 0) base = atomicAdd(&lcnt[nxt][0], c);
                base = __shfl(base, 0);
                if (ns1 != 0.f) {
                    int pos = base + __popcll(m1 & ((1ull << lane) - 1ull));
                    lst1s[nxt][((pos & 7) << 5) + (pos >> 3)] = h;
                }
            }
        } else {
            if (i >= 1 && i <= TT) {
                int ir12 = ((pp12[0][h] + pp12[1][h]) + (pp12[2][h] + pp12[3][h]))
                         + ((pp12[4][h] + pp12[5][h]) + (pp12[6][h] + pp12[7][h]));
                int ir22 = ((pp22[0][h] + pp22[1][h]) + (pp22[2][h] + pp22[3][h]))
                         + ((pp22[4][h] + pp22[5][h]) + (pp22[6][h] + pp22[7][h]));
                float r23 = (float)(ir22 + ir12) * IQSCALE;
                bb2v = ro2 * bb2v + BETAC * (1.f - ro2) * spk2;
                mem2 = mem2 * alpha2 - bb2v * spk2 + (1.f - alpha2) * (bh2v + r23);
                float ns2 = (mem2 - bb2v - BJ0) > 0.f ? 1.f : 0.f;
                spk2 = ns2;
                unsigned long long m2 = __ballot(ns2 != 0.f ? 1 : 0);
                int c = __popcll(m2);
                int base = 0;
                if (lane == 0) base = atomicAdd(&lcnt[nxt][1], c);
                base = __shfl(base, 0);
                if (ns2 != 0.f) {
                    int pos = base + __popcll(m2 & ((1ull << lane) - 1ull));
                    lst2s[nxt][((pos & 7) << 5) + (pos >> 3)] = h;
                }
            }
            if ((h < DOUT) && (i >= 2)) {
                float ro = ((pro[0][h] + pro[1][h]) + (pro[2][h] + pro[3][h]))
                         + ((pro[4][h] + pro[5][h]) + (pro[6][h] + pro[7][h]));
                memo = memo * alpo + (1.f - alpo) * (bov + ro);
                __builtin_nontemporal_store(memo, MoB + (size_t)(i - 2) * DOUT + h);
            }
        }
        BARRIER_LDS();                                 // B2: lists ready

        xp_cur = xp_nxt;
    }
}

// ---------------------------------------------------------------------------
// soft_k: out[b][h] = Σ_t softmax(Mo[b][t])[h].  One thread per timestep row.
// ---------------------------------------------------------------------------
__global__ __launch_bounds__(256) void soft_k(const float* __restrict__ Mo,
                                              float* __restrict__ out) {
    const int b = blockIdx.x;
    const int t = threadIdx.x;
    __shared__ float sm[TT][DOUT];

    if (t < TT) {
        const float* row = Mo + ((size_t)b * TT + t) * DOUT;
        float v[DOUT];
        #pragma unroll
        for (int k = 0; k < DOUT; k += 4) {
            float4 r = *(const float4*)(row + k);
            v[k] = r.x; v[k + 1] = r.y; v[k + 2] = r.z; v[k + 3] = r.w;
        }
        float mx = v[0];
        #pragma unroll
        for (int j = 1; j < DOUT; ++j) mx = fmaxf(mx, v[j]);
        float s = 0.f;
        #pragma unroll
        for (int j = 0; j < DOUT; ++j) { v[j] = __expf(v[j] - mx); s += v[j]; }
        float inv = 1.0f / s;
        #pragma unroll
        for (int j = 0; j < DOUT; ++j) sm[t][j] = v[j] * inv;
    }
    __syncthreads();
    if (t < DOUT) {
        float acc = 0.f;
        for (int tt = 0; tt < TT; ++tt) acc += sm[tt][t];
        out[b * DOUT + t] = acc;
    }
}

extern "C" void kernel_launch(void* const* d_in, const int* in_sizes, int n_in,
                              void* d_out, int out_size, void* d_ws, size_t ws_size,
                              hipStream_t stream) {
    const float* x          = (const float*)d_in[0];
    const float* w_i2h1     = (const float*)d_in[1];
    const float* w_h12h1    = (const float*)d_in[2];
    const float* w_h12h2    = (const float*)d_in[3];
    const float* w_h22h2    = (const float*)d_in[4];
    const float* w_h2o      = (const float*)d_in[5];
    const float* b_h1       = (const float*)d_in[6];
    const float* b_h2       = (const float*)d_in[7];
    const float* b_o        = (const float*)d_in[8];
    const float* tau_adp_h1 = (const float*)d_in[9];
    const float* tau_adp_h2 = (const float*)d_in[10];
    const float* tau_m_h1   = (const float*)d_in[11];
    const float* tau_m_h2   = (const float*)d_in[12];
    const float* tau_m_o    = (const float*)d_in[13];

    signed char* cws = (signed char*)d_ws;
    short* sws = (short*)d_ws;
    int*   iws = (int*)d_ws;
    float* fws = (float*)d_ws;
    const signed char* Bh = cws;
    const signed char* Bl = cws + COFF_BL;
    const int*   sP12 = iws + IOFF_P12;
    const short* sT22 = sws + SOFF_T22;
    float* wT2o = fws + FOFF_W2O;
    float* Xp   = fws + FOFF_XP;
    float* Mo   = fws + FOFF_MO;

    transpose_all_k<<<(N_TRANS + 255) / 256, 256, 0, stream>>>(
        w_i2h1, w_h12h1, w_h12h2, w_h22h2, w_h2o, cws, sws, iws, fws);

    xgemm_k<<<(BB * TT) / 32, 256, 0, stream>>>(x, Bh, Bl, b_h1, Xp);

    rec_k<<<BB, 512, 0, stream>>>(Xp, sP12, sT22, wT2o,
                                  b_h2, b_o, tau_adp_h1, tau_adp_h2,
                                  tau_m_h1, tau_m_h2, tau_m_o, Mo);

    soft_k<<<BB, 256, 0, stream>>>(Mo, (float*)d_out);
}

// Round 5
// 689.557 us; speedup vs baseline: 1.4308x; 1.0932x over previous
//
#include <hip/hip_runtime.h>
#include <cstdint>
#include <cstddef>

#define BB 256
#define TT 250
#define DIN 700
#define H1 256
#define H2 256
#define DOUT 20
#define BJ0 0.01f
#define BETAC 1.8f
#define IQSCALE 3.814697265625e-06f   // 2^-18

typedef float f32x4 __attribute__((ext_vector_type(4)));
typedef int   i32x4 __attribute__((ext_vector_type(4)));

// ---------------------------------------------------------------------------
// Workspace layout (bytes):
//   Bh   [256*704] i8  @ 0         hi8 of q18(w_i2h1), k-pad 700..703 = 0
//   Bl   [256*704] i8  @ 180224    lo8 (q = 256*hi + lo, exact)
//   sT11 [256*256] s16 @ 360448    sT11[d*256+h] = q18(w_h12h1[h][d])
//   sT12 [256*256] s16 @ 491520    q18(w_h12h2[h][d])
//   sT22 [256*256] s16 @ 622592    q18(w_h22h2[h][d])
//   w2o  [256*20]  f32 @ 753664    w2o[j*20+o] = w_h2o[o][j]
//   Xp   [64000*256] f32 @ 774144
//   Mo   [256*250*20] f32 @ 66310144
// ---------------------------------------------------------------------------
#define COFF_BL  180224
#define SOFF_T11 180224
#define SOFF_T12 245760
#define SOFF_T22 311296
#define FOFF_W2O 188416
#define FOFF_XP  193536
#define FOFF_MO  16577536
#define N_TRANS  381952

// LDS-only drain + raw barrier: all cross-thread traffic in rec_k is LDS
// (lists, counters); global loads/stores stay in flight across barriers.
#define BARRIER_LDS() asm volatile("s_waitcnt lgkmcnt(0)\n\ts_barrier" ::: "memory")

__device__ __forceinline__ short q18(float w) {
    float s = w * 262144.0f;
    s = fminf(fmaxf(s, -32767.0f), 32767.0f);
    return (short)__float2int_rn(s);
}

__global__ void transpose_all_k(const float* __restrict__ w_i2h1,
                                const float* __restrict__ w_h12h1,
                                const float* __restrict__ w_h12h2,
                                const float* __restrict__ w_h22h2,
                                const float* __restrict__ w_h2o,
                                signed char* __restrict__ cws,
                                short* __restrict__ sws,
                                float* __restrict__ fws) {
    int i = blockIdx.x * blockDim.x + threadIdx.x;
    if (i < 180224) {               // Bh/Bl: [h=0..255][k=0..703]
        int h = i / 704, k = i - h * 704;
        int q = (k < DIN) ? (int)q18(w_i2h1[h * DIN + k]) : 0;
        q = q > 32639 ? 32639 : (q < -32640 ? -32640 : q);  // keep hi8 in range
        int hi = (q + 128) >> 8;
        int lo = q - (hi << 8);
        cws[i] = (signed char)hi;
        cws[COFF_BL + i] = (signed char)lo;
        return;
    }
    i -= 180224;
    if (i < 65536) { int d = i >> 8, h = i & 255;
        sws[SOFF_T11 + i] = q18(w_h12h1[h * H1 + d]); return; }
    i -= 65536;
    if (i < 65536) { int d = i >> 8, h = i & 255;
        sws[SOFF_T12 + i] = q18(w_h12h2[h * H1 + d]); return; }
    i -= 65536;
    if (i < 65536) { int d = i >> 8, h = i & 255;
        sws[SOFF_T22 + i] = q18(w_h22h2[h * H2 + d]); return; }
    i -= 65536;
    if (i < 5120)  { int j = i / 20, o = i % 20;
        fws[FOFF_W2O + i] = w_h2o[o * H2 + j]; return; }
}

// ---------------------------------------------------------------------------
// xgemm_k: Xp = x @ W^T + b_h1 via two exact i8 MFMA GEMMs (unchanged R4).
// ---------------------------------------------------------------------------
__global__ __launch_bounds__(256) void xgemm_k(const float* __restrict__ x,
                                               const signed char* __restrict__ Bh,
                                               const signed char* __restrict__ Bl,
                                               const float* __restrict__ b_h1,
                                               float* __restrict__ Xp) {
    const int t    = threadIdx.x;
    const int lane = t & 63;
    const int w    = t >> 6;             // wave 0..3 -> cols [64w, 64w+64)
    const int m0   = blockIdx.x * 32;

    __shared__ __align__(16) signed char Asub[32 * 720];
    __shared__ __align__(16) signed char Bhs[256 * 80];
    __shared__ __align__(16) signed char Bls[256 * 80];

    #pragma unroll
    for (int it = 0; it < 22; ++it) {
        int flat = it * 256 + t;
        int row  = flat / 176;
        int c4   = flat - row * 176;
        unsigned int pk = 0u;
        if (c4 < 175) {
            const float* xr = x + (size_t)(m0 + row) * DIN;
            float4 f = *(const float4*)(xr + (c4 << 2));
            pk = (f.x != 0.f ? 1u : 0u)
               | (f.y != 0.f ? 1u : 0u) << 8
               | (f.z != 0.f ? 1u : 0u) << 16
               | (f.w != 0.f ? 1u : 0u) << 24;
        }
        *(unsigned int*)(Asub + row * 720 + (c4 << 2)) = pk;
    }

    i32x4 acch[2][4], accl[2][4];
    #pragma unroll
    for (int mt = 0; mt < 2; ++mt)
        #pragma unroll
        for (int nt = 0; nt < 4; ++nt) {
            acch[mt][nt] = (i32x4){0, 0, 0, 0};
            accl[mt][nt] = (i32x4){0, 0, 0, 0};
        }

    const int arow  = lane & 15;
    const int kg16  = (lane >> 4) << 4;
    const int bcol0 = w << 6;

    for (int ks = 0; ks < 11; ++ks) {
        __syncthreads();
        #pragma unroll
        for (int it2 = 0; it2 < 4; ++it2) {
            int row = it2 * 64 + (t >> 2);
            int ch  = (t & 3) << 4;
            int go  = row * 704 + ks * 64 + ch;
            *(int4*)(Bhs + row * 80 + ch) = *(const int4*)(Bh + go);
            *(int4*)(Bls + row * 80 + ch) = *(const int4*)(Bl + go);
        }
        __syncthreads();

        const int ko = ks * 64 + kg16;
        i32x4 a0 = *(const i32x4*)(Asub + arow * 720 + ko);
        i32x4 a1 = *(const i32x4*)(Asub + (16 + arow) * 720 + ko);
        #pragma unroll
        for (int nt = 0; nt < 4; ++nt) {
            const int bb = (bcol0 + nt * 16 + arow) * 80 + kg16;
            i32x4 bhf = *(const i32x4*)(Bhs + bb);
            i32x4 blf = *(const i32x4*)(Bls + bb);
            acch[0][nt] = __builtin_amdgcn_mfma_i32_16x16x64_i8(a0, bhf, acch[0][nt], 0, 0, 0);
            acch[1][nt] = __builtin_amdgcn_mfma_i32_16x16x64_i8(a1, bhf, acch[1][nt], 0, 0, 0);
            accl[0][nt] = __builtin_amdgcn_mfma_i32_16x16x64_i8(a0, blf, accl[0][nt], 0, 0, 0);
            accl[1][nt] = __builtin_amdgcn_mfma_i32_16x16x64_i8(a1, blf, accl[1][nt], 0, 0, 0);
        }
    }

    const int crb = (lane >> 4) << 2;
    #pragma unroll
    for (int nt = 0; nt < 4; ++nt) {
        int col = bcol0 + nt * 16 + arow;
        float bias = b_h1[col];
        #pragma unroll
        for (int mt = 0; mt < 2; ++mt) {
            #pragma unroll
            for (int r = 0; r < 4; ++r) {
                int row = m0 + mt * 16 + crb + r;
                int ir = (acch[mt][nt][r] << 8) + accl[mt][nt][r];
                __builtin_nontemporal_store(bias + (float)ir * IQSCALE,
                                            Xp + (size_t)row * H1 + col);
            }
        }
    }
}

// ---------------------------------------------------------------------------
// rec_k: ONE barrier per iteration. 512 threads:
//   waves 0-3 (L1): lane owns layer-1 col c=64w+lane. Gathers ir11 over lst1
//     from global sT11 (entry e wave-uniform -> coalesced 128B row slice).
//     Lanes<5 additionally gather output col oc=5w+lane over lst2 (LDS w2o).
//   waves 4-7 (L2): lane owns layer-2 col c. Gathers ir12 over lst1 (global
//     sT12) + ir22 over lst2 (LDS sT22L).
//   Each lane has its full input sum -> update in-registers, per-wave ballot,
//   one LDS atomicAdd appends spikes to the NEXT list buffer.
//   Counters: 4-slot rotation -- read C[i&3], append C[(i+1)&3], zero
//   C[(i+2)&3] -- all distinct per iteration => race-free with one barrier.
//   Lists zero-initialized so stale slots beyond tot are in-bounds rows;
//   remainder chunk handled by uniform branches (values never added).
//   Integer spike path == previous rounds (same q18 values, int sums).
// LDS: 131072 + 20480 + 2*1024*2 + 32 = 155,680 B (1 block/CU).
// ---------------------------------------------------------------------------
__global__ __launch_bounds__(512) void rec_k(
    const float* __restrict__ Xp,
    const short* __restrict__ sT11, const short* __restrict__ sT12,
    const short* __restrict__ sT22, const float* __restrict__ wT2o,
    const float* __restrict__ b_h2, const float* __restrict__ b_o,
    const float* __restrict__ tau_adp_h1, const float* __restrict__ tau_adp_h2,
    const float* __restrict__ tau_m_h1, const float* __restrict__ tau_m_h2,
    const float* __restrict__ tau_m_o,
    float* __restrict__ Mo) {
    const int tid  = threadIdx.x;        // 0..511
    const int lane = tid & 63;
    const int w    = tid >> 6;           // wave 0..7
    const bool isL1 = (w < 4);
    const int c    = ((w & 3) << 6) + lane;   // owned column within layer
    const int b    = blockIdx.x;
    const float* __restrict__ XpB = Xp + (size_t)b * TT * H1;
    float* __restrict__ MoB = Mo + (size_t)b * TT * DOUT;

    __shared__ __align__(16) short sT22L[65536];   // 128 KB
    __shared__ __align__(16) float w2oL[5120];     // 20 KB  [j][0..19]
    __shared__ __align__(16) int lst1s[2][256];
    __shared__ __align__(16) int lst2s[2][256];
    __shared__ __align__(16) int lcnt[4][2];       // 4-slot rotation

    // one-time staging
    {
        const int* src = (const int*)sT22;
        int* dst = (int*)sT22L;
        for (int k = tid; k < 32768; k += 512) dst[k] = src[k];
        for (int k = tid; k < 5120; k += 512) w2oL[k] = wT2o[k];
        if (tid < 256) { lst1s[0][tid] = 0; lst1s[1][tid] = 0;
                         lst2s[0][tid] = 0; lst2s[1][tid] = 0; }
        if (tid < 8) ((int*)lcnt)[tid] = 0;
    }

    // per-lane constants (one layer each)
    float alpha, rr, inb = 0.f;
    if (isL1) {
        alpha = expf(-1.0f / tau_m_h1[c]);
        rr    = expf(-1.0f / tau_adp_h1[c]);
    } else {
        alpha = expf(-1.0f / tau_m_h2[c]);
        rr    = expf(-1.0f / tau_adp_h2[c]);
        inb   = b_h2[c];
    }
    const int oc  = ((w & 3) * 5) + lane;          // output col (L1 lanes<5)
    const int ocs = (isL1 && lane < 5) ? oc : 0;
    float alpo = 0.f, bov = 0.f;
    if (isL1 && lane < 5) { alpo = expf(-1.0f / tau_m_o[oc]); bov = b_o[oc]; }

    float mem = 0.f, spk = 0.f, bbv = BJ0;
    float memo = 0.f;

    float xp_cur = 0.f;
    if (isL1) xp_cur = __builtin_nontemporal_load(XpB + c);
    __syncthreads();                       // staging complete (full drain, once)

    for (int i = 0; i <= TT + 1; ++i) {
        const int cur = i & 1, nxt = cur ^ 1;
        const int cc = i & 3, cn = (i + 1) & 3, cz = (i + 2) & 3;

        const int tot1 = lcnt[cc][0];
        const int tot2 = lcnt[cc][1];
        if (tid == 0) { lcnt[cz][0] = 0; lcnt[cz][1] = 0; }

        float xp_nxt = 0.f;
        if (isL1 && i + 1 < TT)
            xp_nxt = __builtin_nontemporal_load(XpB + (size_t)(i + 1) * H1 + c);

        const int* __restrict__ L1l = lst1s[cur];
        const int* __restrict__ L2l = lst2s[cur];

        int acc1 = 0, acc2 = 0;
        float ao = 0.f;

        if (isL1) {
            if (i < TT) {                          // ir11 over lst1 (global)
                const short* colT = sT11 + c;
                int nb = tot1 >> 2, rem = tot1 & 3;
                for (int kk = 0; kk < nb; ++kk) {
                    int4 e = *(const int4*)(L1l + (kk << 2));
                    acc1 += colT[e.x << 8]; acc1 += colT[e.y << 8];
                    acc1 += colT[e.z << 8]; acc1 += colT[e.w << 8];
                }
                if (rem) {
                    int4 e = *(const int4*)(L1l + (nb << 2));
                    acc1 += colT[e.x << 8];
                    if (rem > 1) acc1 += colT[e.y << 8];
                    if (rem > 2) acc1 += colT[e.z << 8];
                }
            }
            if (i >= 2) {                          // output gather over lst2 (LDS)
                int nb = tot2 >> 2, rem = tot2 & 3;
                for (int kk = 0; kk < nb; ++kk) {
                    int4 e = *(const int4*)(L2l + (kk << 2));
                    float v0 = w2oL[e.x * DOUT + ocs];
                    float v1 = w2oL[e.y * DOUT + ocs];
                    float v2 = w2oL[e.z * DOUT + ocs];
                    float v3 = w2oL[e.w * DOUT + ocs];
                    ao += (v0 + v1) + (v2 + v3);
                }
                if (rem) {
                    int4 e = *(const int4*)(L2l + (nb << 2));
                    ao += w2oL[e.x * DOUT + ocs];
                    if (rem > 1) ao += w2oL[e.y * DOUT + ocs];
                    if (rem > 2) ao += w2oL[e.z * DOUT + ocs];
                }
            }
        } else if (i >= 1 && i <= TT) {
            {                                      // ir12 over lst1 (global)
                const short* colT = sT12 + c;
                int nb = tot1 >> 2, rem = tot1 & 3;
                for (int kk = 0; kk < nb; ++kk) {
                    int4 e = *(const int4*)(L1l + (kk << 2));
                    acc1 += colT[e.x << 8]; acc1 += colT[e.y << 8];
                    acc1 += colT[e.z << 8]; acc1 += colT[e.w << 8];
                }
                if (rem) {
                    int4 e = *(const int4*)(L1l + (nb << 2));
                    acc1 += colT[e.x << 8];
                    if (rem > 1) acc1 += colT[e.y << 8];
                    if (rem > 2) acc1 += colT[e.z << 8];
                }
            }
            {                                      // ir22 over lst2 (LDS)
                const short* colL = sT22L + c;
                int nb = tot2 >> 2, rem = tot2 & 3;
                for (int kk = 0; kk < nb; ++kk) {
                    int4 e = *(const int4*)(L2l + (kk << 2));
                    acc2 += colL[e.x << 8]; acc2 += colL[e.y << 8];
                    acc2 += colL[e.z << 8]; acc2 += colL[e.w << 8];
                }
                if (rem) {
                    int4 e = *(const int4*)(L2l + (nb << 2));
                    acc2 += colL[e.x << 8];
                    if (rem > 1) acc2 += colL[e.y << 8];
                    if (rem > 2) acc2 += colL[e.z << 8];
                }
            }
        }

        // ---- update + append (in-registers, per-wave) ----
        if (isL1) {
            if (i < TT) {
                float r1 = (float)acc1 * IQSCALE;
                bbv = rr * bbv + BETAC * (1.f - rr) * spk;
                mem = mem * alpha - bbv * spk + (1.f - alpha) * (xp_cur + r1);
                float ns = (mem - bbv - BJ0) > 0.f ? 1.f : 0.f;
                spk = ns;
                unsigned long long m = __ballot(ns != 0.f ? 1 : 0);
                int base = 0;
                if (lane == 0) base = atomicAdd(&lcnt[cn][0], __popcll(m));
                base = __shfl(base, 0);
                if (ns != 0.f)
                    lst1s[nxt][base + __popcll(m & ((1ull << lane) - 1ull))] = c;
            }
            if (lane < 5 && i >= 2) {
                memo = memo * alpo + (1.f - alpo) * (bov + ao);
                __builtin_nontemporal_store(memo, MoB + (size_t)(i - 2) * DOUT + oc);
            }
        } else if (i >= 1 && i <= TT) {
            float r23 = (float)(acc1 + acc2) * IQSCALE;
            bbv = rr * bbv + BETAC * (1.f - rr) * spk;
            mem = mem * alpha - bbv * spk + (1.f - alpha) * (inb + r23);
            float ns = (mem - bbv - BJ0) > 0.f ? 1.f : 0.f;
            spk = ns;
            unsigned long long m = __ballot(ns != 0.f ? 1 : 0);
            int base = 0;
            if (lane == 0) base = atomicAdd(&lcnt[cn][1], __popcll(m));
            base = __shfl(base, 0);
            if (ns != 0.f)
                lst2s[nxt][base + __popcll(m & ((1ull << lane) - 1ull))] = c;
        }

        BARRIER_LDS();                             // lists + counters published
        xp_cur = xp_nxt;
    }
}

// ---------------------------------------------------------------------------
// soft_k: out[b][h] = Σ_t softmax(Mo[b][t])[h].  One thread per timestep row.
// ---------------------------------------------------------------------------
__global__ __launch_bounds__(256) void soft_k(const float* __restrict__ Mo,
                                              float* __restrict__ out) {
    const int b = blockIdx.x;
    const int t = threadIdx.x;
    __shared__ float sm[TT][DOUT];

    if (t < TT) {
        const float* row = Mo + ((size_t)b * TT + t) * DOUT;
        float v[DOUT];
        #pragma unroll
        for (int k = 0; k < DOUT; k += 4) {
            float4 r = *(const float4*)(row + k);
            v[k] = r.x; v[k + 1] = r.y; v[k + 2] = r.z; v[k + 3] = r.w;
        }
        float mx = v[0];
        #pragma unroll
        for (int j = 1; j < DOUT; ++j) mx = fmaxf(mx, v[j]);
        float s = 0.f;
        #pragma unroll
        for (int j = 0; j < DOUT; ++j) { v[j] = __expf(v[j] - mx); s += v[j]; }
        float inv = 1.0f / s;
        #pragma unroll
        for (int j = 0; j < DOUT; ++j) sm[t][j] = v[j] * inv;
    }
    __syncthreads();
    if (t < DOUT) {
        float acc = 0.f;
        for (int tt = 0; tt < TT; ++tt) acc += sm[tt][t];
        out[b * DOUT + t] = acc;
    }
}

extern "C" void kernel_launch(void* const* d_in, const int* in_sizes, int n_in,
                              void* d_out, int out_size, void* d_ws, size_t ws_size,
                              hipStream_t stream) {
    const float* x          = (const float*)d_in[0];
    const float* w_i2h1     = (const float*)d_in[1];
    const float* w_h12h1    = (const float*)d_in[2];
    const float* w_h12h2    = (const float*)d_in[3];
    const float* w_h22h2    = (const float*)d_in[4];
    const float* w_h2o      = (const float*)d_in[5];
    const float* b_h1       = (const float*)d_in[6];
    const float* b_h2       = (const float*)d_in[7];
    const float* b_o        = (const float*)d_in[8];
    const float* tau_adp_h1 = (const float*)d_in[9];
    const float* tau_adp_h2 = (const float*)d_in[10];
    const float* tau_m_h1   = (const float*)d_in[11];
    const float* tau_m_h2   = (const float*)d_in[12];
    const float* tau_m_o    = (const float*)d_in[13];

    signed char* cws = (signed char*)d_ws;
    short* sws = (short*)d_ws;
    float* fws = (float*)d_ws;
    const signed char* Bh = cws;
    const signed char* Bl = cws + COFF_BL;
    const short* sT11 = sws + SOFF_T11;
    const short* sT12 = sws + SOFF_T12;
    const short* sT22 = sws + SOFF_T22;
    float* wT2o = fws + FOFF_W2O;
    float* Xp   = fws + FOFF_XP;
    float* Mo   = fws + FOFF_MO;

    transpose_all_k<<<N_TRANS / 256, 256, 0, stream>>>(
        w_i2h1, w_h12h1, w_h12h2, w_h22h2, w_h2o, cws, sws, fws);

    xgemm_k<<<(BB * TT) / 32, 256, 0, stream>>>(x, Bh, Bl, b_h1, Xp);

    rec_k<<<BB, 512, 0, stream>>>(Xp, sT11, sT12, sT22, wT2o,
                                  b_h2, b_o, tau_adp_h1, tau_adp_h2,
                                  tau_m_h1, tau_m_h2, tau_m_o, Mo);

    soft_k<<<BB, 256, 0, stream>>>(Mo, (float*)d_out);
}